// Round 7
// baseline (602.614 us; speedup 1.0000x reference)
//
#include <hip/hip_runtime.h>
#include <hip/hip_bf16.h>

typedef unsigned short u16;
typedef unsigned int u32;
typedef __attribute__((ext_vector_type(8))) short short8;    // 8 bf16 MFMA A/B frag
typedef __attribute__((ext_vector_type(4))) float f32x4;
typedef __attribute__((ext_vector_type(16))) float f32x16;   // 32x32 MFMA C/D frag

#define KS1 1.44269504f   // log2(e)
#define KS2 2.88539008f   // 2*log2(e)

__device__ __forceinline__ float bf2f(u16 u) {
    union { u32 i; float f; } v; v.i = ((u32)u) << 16; return v.f;
}
__device__ __forceinline__ u16 f2bf(float f) {            // RNE
    union { float f; u32 i; } v; v.f = f;
    u32 r = v.i + 0x7fffu + ((v.i >> 16) & 1u);
    return (u16)(r >> 16);
}
// pack two f32 -> two bf16 (truncation) in ONE v_perm
__device__ __forceinline__ u32 pack_bf2(float lo, float hi) {
    return __builtin_amdgcn_perm(__float_as_uint(hi), __float_as_uint(lo), 0x07060302u);
}
__device__ __forceinline__ void lds_fence() {
    __asm__ __volatile__("s_waitcnt lgkmcnt(0)" ::: "memory");
}

// ---------------------------------------------------------------------------
// k_pre: [0,gb) xp1 GEMM; [gb,gb+eb) edge cast; [gb+eb,+4) scaled weight copies
// ---------------------------------------------------------------------------
__global__ __launch_bounds__(256) void k_pre(
    const u16* __restrict__ X, const u16* __restrict__ pw, const u16* __restrict__ pb,
    u16* __restrict__ XP, int M, int gb,
    const int* __restrict__ e, float* __restrict__ eout, int n4, int eb,
    const u16* __restrict__ w1i, const u16* __restrict__ w1h,
    const u16* __restrict__ w2i, const u16* __restrict__ w2h,
    u16* __restrict__ wss)
{
    const int bid = blockIdx.x;
    const int tid = threadIdx.x;
    if (bid >= gb + eb) {
        int mi = bid - gb - eb;
        const u16* Wsrc = (mi == 0) ? w1i : (mi == 1) ? w1h : (mi == 2) ? w2i : w2h;
        u16* Wdst = wss + (size_t)mi * 16384;
        for (int idx = tid; idx < 16384; idx += 256) {
            int row = idx >> 6;
            float sc = (row >= 128 && row < 192) ? KS2 : KS1;
            Wdst[idx] = f2bf(bf2f(Wsrc[idx]) * sc);
        }
        return;
    }
    if (bid >= gb) {
        int i = (bid - gb) * 256 + tid;
        if (i < n4) {
            int4 v = *(const int4*)(e + (size_t)i * 4);
            float4 o;
            o.x = (float)v.x; o.y = (float)v.y; o.z = (float)v.z; o.w = (float)v.w;
            *(float4*)(eout + (size_t)i * 4) = o;
        }
        return;
    }
    const int lane = tid & 63;
    const int wave = tid >> 6;
    const int row0 = (bid * 4 + wave) * 16;
    if (row0 >= M) return;
    const int col  = lane & 15;
    const int quad = lane >> 4;

    f32x4 c1[4];
#pragma unroll
    for (int jt = 0; jt < 4; ++jt) c1[jt] = (f32x4){0.f, 0.f, 0.f, 0.f};
    {
        const u16* xrow = X  + (size_t)(row0 + col) * 64 + quad * 8;
        const u16* wrow = pw + (size_t)col * 64 + quad * 8;
#pragma unroll
        for (int kc = 0; kc < 64; kc += 32) {
            short8 a = *(const short8*)(xrow + kc);
#pragma unroll
            for (int jt = 0; jt < 4; ++jt) {
                short8 b = *(const short8*)(wrow + (size_t)jt * 16 * 64 + kc);
                c1[jt] = __builtin_amdgcn_mfma_f32_16x16x32_bf16(a, b, c1[jt], 0, 0, 0);
            }
        }
    }
#pragma unroll
    for (int jt = 0; jt < 4; ++jt) {
        float bias = bf2f(pb[jt * 16 + col]);
#pragma unroll
        for (int r = 0; r < 4; ++r) {
            float v = fmaxf(c1[jt][r] + bias, 0.f);
            XP[(size_t)(row0 + quad * 4 + r) * 64 + jt * 16 + col] = f2bf(v);
        }
    }
}

// ---------------------------------------------------------------------------
// LSTM aggregation v3: 32x32x16 MFMA, 32 nodes/wave (halved LDS traffic/node).
//   gates^T[256x32] = Wih'@xp[src]^T + Whh'@h^T + bias' (scaled domain)
// - Wih'+Whh' LDS frag tables (64KB); bias' as 1KB LDS C-operand frags
//   (broadcast reads, zero VGPR cost — acc is 128 regs, bias regs won't fit).
// - C layout: node=lane&31, gate_row=(r&3)+8*(r>>2)+4*hi  (hi=lane>>5)
// - h C-layout -> B-frag (k=hi*8+j) via 32 ds_bpermute + 16 cndmask.
// - xp gather: 4x16B per lane = B frags direct, prefetched one step.
// NOTE: no waves/EU cap (round 4: cap => catastrophic scratch spill).
// ---------------------------------------------------------------------------
__global__ __launch_bounds__(256) void lstm_kernel(
    const u16* __restrict__ xp,    // [N,64] bf16 (unscaled)
    const int* __restrict__ src,   // [N*16]
    const u16* __restrict__ wihs,  // [256,64] scaled copy
    const u16* __restrict__ whhs,  // [256,64] scaled copy
    const u16* __restrict__ bih, const u16* __restrict__ bhh,  // [256] originals
    u16* __restrict__ Hout,        // [N,64] bf16
    int N)
{
    __shared__ u16 lds_w[32768];   // 64KB: wih frags @0, whh frags @16384(u16)
    __shared__ float lds_b[256];   // 1KB: bias C-frags [jt][hi][a*4+b]

    const int tid  = threadIdx.x;
    const int lane = tid & 63;
    const int wave = tid >> 6;
    const int col  = lane & 31;    // node within wave
    const int hi   = lane >> 5;

    const int node0 = (blockIdx.x * 4 + wave) * 32;
    const int node  = node0 + col;
    const bool nact = node < N;
    const int nodeg = nact ? node : 0;

    // bias staging: thread tid -> gate j=tid; C-frag slot [jt][hi][a*4+b]
    {
        int j = tid;
        int jt = j >> 5, row32 = j & 31;
        int a = row32 >> 3, hb_ = (row32 >> 2) & 1, b = row32 & 3;
        float sc = (jt == 4 || jt == 5) ? KS2 : KS1;
        lds_b[jt * 32 + hb_ * 16 + a * 4 + b] = (bf2f(bih[j]) + bf2f(bhh[j])) * sc;
    }
    // weight frag staging: frag(tbl,jt,kc) lane l holds W[jt*32+(l&31)][kc*16+(l>>5)*8 ..+8)
    for (int s = tid; s < 4096; s += 256) {
        int tbl = s >> 11, f = (s >> 6) & 31, l = s & 63;
        int jt = f >> 2, kc = f & 3;
        const u16* W = tbl ? whhs : wihs;
        int row = jt * 32 + (l & 31);
        int k0  = kc * 16 + (l >> 5) * 8;
        *(short8*)(lds_w + (size_t)s * 8) = *(const short8*)(W + row * 64 + k0);
    }

    // node indices: lane covers steps hi*8 .. hi*8+7 in two int4
    const int* sp = src + (size_t)nodeg * 16;
    int4 si0 = *(const int4*)(sp + hi * 8);
    int4 si1 = *(const int4*)(sp + hi * 8 + 4);

    // t=0 xp prefetch (B-frag direct): chunk kc = 16B at elem kc*16 + hi*8
    short8 xb[4];
    {
        int s0 = __shfl(si0.x, col, 64);   // step 0 index from hi=0 half
        const u16* px = xp + (size_t)s0 * 64 + hi * 8;
#pragma unroll
        for (int kc = 0; kc < 4; ++kc) xb[kc] = *(const short8*)(px + kc * 16);
    }
    __syncthreads();
    if (node0 >= N) return;
    // waves fully independent from here (lds read-only)

    short8 hb[4];
#pragma unroll
    for (int kc = 0; kc < 4; ++kc) hb[kc] = (short8){0,0,0,0,0,0,0,0};

    float c_[32];   // scaled-domain cell state: c_[jt0*16 + r]
#pragma unroll
    for (int i = 0; i < 32; ++i) c_[i] = 0.f;

#pragma unroll 1
    for (int t = 0; t < 16; ++t) {
        // 1) Wih GEMM; bias enters via the C operand (LDS broadcast frags)
        f32x16 acc[8];
#pragma unroll
        for (int jt = 0; jt < 8; ++jt) {
            union { f32x16 v; f32x4 q[4]; } a;
            const float* bp = lds_b + jt * 32 + hi * 16;
#pragma unroll
            for (int c = 0; c < 4; ++c) a.q[c] = *(const f32x4*)(bp + c * 4);
#pragma unroll
            for (int kc = 0; kc < 4; ++kc) {
                short8 w = *(const short8*)(lds_w + (size_t)(((jt * 4 + kc) * 64 + lane)) * 8);
                a.v = __builtin_amdgcn_mfma_f32_32x32x16_bf16(w, xb[kc], a.v, 0, 0, 0);
            }
            acc[jt] = a.v;
        }
        // 2) prefetch next step's xp row (xb consumed above)
        if (t < 15) {
            int tn = t + 1;
            int within = tn & 7;
            int cv = (within & 4)
                ? ((within & 2) ? ((within & 1) ? si1.w : si1.z)
                                : ((within & 1) ? si1.y : si1.x))
                : ((within & 2) ? ((within & 1) ? si0.w : si0.z)
                                : ((within & 1) ? si0.y : si0.x));
            int sn = __shfl(cv, col + ((tn >> 3) << 5), 64);
            const u16* px = xp + (size_t)sn * 64 + hi * 8;
#pragma unroll
            for (int kc = 0; kc < 4; ++kc) xb[kc] = *(const short8*)(px + kc * 16);
        }
        // 3) Whh GEMM
        if (t > 0) {
#pragma unroll
            for (int jt = 0; jt < 8; ++jt) {
                f32x16 a = acc[jt];
#pragma unroll
                for (int kc = 0; kc < 4; ++kc) {
                    short8 w = *(const short8*)(lds_w + (size_t)(16384 + ((jt * 4 + kc) * 64 + lane) * 8));
                    a = __builtin_amdgcn_mfma_f32_32x32x16_bf16(w, hb[kc], a, 0, 0, 0);
                }
                acc[jt] = a;
            }
        }
        // 4) nonlinearity (scaled domain). gate tiles: i=0,1 f=2,3 g=4,5 o=6,7
        u32 hword[16];   // [jt0*8 + a*2 + wbit]: dims jt0*32+8a+4hi + {2wbit, +1}
#pragma unroll
        for (int jt0 = 0; jt0 < 2; ++jt0) {
#pragma unroll
            for (int a = 0; a < 4; ++a) {
                float hv[4];
#pragma unroll
                for (int b = 0; b < 4; ++b) {
                    int r = a * 4 + b;
                    float iv = acc[jt0 + 0][r];
                    float fv = acc[jt0 + 2][r];
                    float gv = acc[jt0 + 4][r];
                    float ov = acc[jt0 + 6][r];
                    float e_i = __builtin_amdgcn_exp2f(-iv);
                    float e_f = __builtin_amdgcn_exp2f(-fv);
                    float e_g = __builtin_amdgcn_exp2f(gv);
                    float sf  = __builtin_amdgcn_rcpf(1.0f + e_f);
                    float rig = __builtin_amdgcn_rcpf((1.0f + e_i) * (1.0f + e_g));
                    float tt  = __builtin_fmaf(e_g, KS2, -KS2);
                    float cn  = __builtin_fmaf(sf, c_[jt0 * 16 + r], tt * rig);
                    c_[jt0 * 16 + r] = cn;
                    float e_c = __builtin_amdgcn_exp2f(cn);
                    float e_o = __builtin_amdgcn_exp2f(-ov);
                    float roc = __builtin_amdgcn_rcpf((1.0f + e_o) * (1.0f + e_c));
                    hv[b] = (e_c - 1.0f) * roc;
                }
                u32 w0 = pack_bf2(hv[0], hv[1]);
                u32 w1 = pack_bf2(hv[2], hv[3]);
                hword[jt0 * 8 + a * 2 + 0] = w0;
                hword[jt0 * 8 + a * 2 + 1] = w1;
                if (t == 15 && nact) {
                    uint2 o; o.x = w0; o.y = w1;
                    *(uint2*)(Hout + (size_t)node * 64 + jt0 * 32 + a * 8 + hi * 4) = o;
                }
            }
        }
        // 5) h C-layout -> B-frag via ds_bpermute:
        //    target (kc, w): src lane = col + 32*(w>>1),
        //    src word = kc*4 + 2*hi_target + (w&1)  (select by hi via cndmask)
        if (t < 15) {
#pragma unroll
            for (int kc = 0; kc < 4; ++kc) {
                union { u32 w[4]; short8 v; } xch;
#pragma unroll
                for (int w = 0; w < 4; ++w) {
                    int idx = (col + ((w >> 1) << 5)) << 2;
                    u32 lo = (u32)__builtin_amdgcn_ds_bpermute(idx, (int)hword[kc * 4 + (w & 1)]);
                    u32 hh = (u32)__builtin_amdgcn_ds_bpermute(idx, (int)hword[kc * 4 + 2 + (w & 1)]);
                    xch.w[w] = hi ? hh : lo;
                }
                hb[kc] = xch.v;
            }
        }
    }
}

// ---------------------------------------------------------------------------
// k_mid: Y1 = relu(H@llw^T + X2@lrw^T + llb) -> global + LDS
//        xp2 = relu(Y1@pw^T + pb)            -> global
// ---------------------------------------------------------------------------
__global__ __launch_bounds__(256) void k_mid(
    const u16* __restrict__ H, const u16* __restrict__ X2,
    const u16* __restrict__ llw, const u16* __restrict__ llb,
    const u16* __restrict__ lrw,
    const u16* __restrict__ pw, const u16* __restrict__ pb,
    u16* __restrict__ Y1, u16* __restrict__ XP2, int M)
{
    __shared__ u16 t_lds[4][16 * 64];

    const int lane = threadIdx.x & 63;
    const int wave = threadIdx.x >> 6;
    const int row0 = (blockIdx.x * 4 + wave) * 16;
    if (row0 >= M) return;
    const int col  = lane & 15;
    const int quad = lane >> 4;
    u16* tl = t_lds[wave];

    f32x4 c0[4];
#pragma unroll
    for (int jt = 0; jt < 4; ++jt) c0[jt] = (f32x4){0.f, 0.f, 0.f, 0.f};
#pragma unroll
    for (int pass = 0; pass < 2; ++pass) {
        const u16* Xp = pass ? X2 : H;
        const u16* Wp = pass ? lrw : llw;
        const u16* xrow = Xp + (size_t)(row0 + col) * 64 + quad * 8;
        const u16* wrow = Wp + (size_t)col * 64 + quad * 8;
#pragma unroll
        for (int kc = 0; kc < 64; kc += 32) {
            short8 a = *(const short8*)(xrow + kc);
#pragma unroll
            for (int jt = 0; jt < 4; ++jt) {
                short8 b = *(const short8*)(wrow + (size_t)jt * 16 * 64 + kc);
                c0[jt] = __builtin_amdgcn_mfma_f32_16x16x32_bf16(a, b, c0[jt], 0, 0, 0);
            }
        }
    }
#pragma unroll
    for (int jt = 0; jt < 4; ++jt) {
        float bias = bf2f(llb[jt * 16 + col]);
#pragma unroll
        for (int r = 0; r < 4; ++r) {
            float v = fmaxf(c0[jt][r] + bias, 0.f);
            u16 vb = f2bf(v);
            int row = quad * 4 + r;
            int k   = jt * 16 + col;
            Y1[(size_t)(row0 + row) * 64 + k] = vb;
            tl[row * 64 + ((((k >> 3) ^ (row & 7))) << 3) + (k & 7)] = vb;
        }
    }
    lds_fence();

    short8 a0f, a1f;
    {
        int c0i = (0 * 4 + quad) ^ (col & 7);
        int c1i = (1 * 4 + quad) ^ (col & 7);
        a0f = *(const short8*)(tl + col * 64 + c0i * 8);
        a1f = *(const short8*)(tl + col * 64 + c1i * 8);
    }
    f32x4 c1[4];
#pragma unroll
    for (int jt = 0; jt < 4; ++jt) c1[jt] = (f32x4){0.f, 0.f, 0.f, 0.f};
    {
        const u16* wrow = pw + (size_t)col * 64 + quad * 8;
#pragma unroll
        for (int jt = 0; jt < 4; ++jt) {
            short8 b0 = *(const short8*)(wrow + (size_t)jt * 16 * 64);
            c1[jt] = __builtin_amdgcn_mfma_f32_16x16x32_bf16(a0f, b0, c1[jt], 0, 0, 0);
            short8 b1 = *(const short8*)(wrow + (size_t)jt * 16 * 64 + 32);
            c1[jt] = __builtin_amdgcn_mfma_f32_16x16x32_bf16(a1f, b1, c1[jt], 0, 0, 0);
        }
    }
#pragma unroll
    for (int jt = 0; jt < 4; ++jt) {
        float bias = bf2f(pb[jt * 16 + col]);
#pragma unroll
        for (int r = 0; r < 4; ++r) {
            float v = fmaxf(c1[jt][r] + bias, 0.f);
            XP2[(size_t)(row0 + quad * 4 + r) * 64 + jt * 16 + col] = f2bf(v);
        }
    }
}

// ---------------------------------------------------------------------------
// k_post: Y2[128] (LDS) -> T1[192] -> T2[64] -> out[64] f32
// ---------------------------------------------------------------------------
__global__ __launch_bounds__(256) void k_post(
    const u16* __restrict__ H, const u16* __restrict__ X2,
    const u16* __restrict__ llw, const u16* __restrict__ llb,
    const u16* __restrict__ lrw,
    const u16* __restrict__ w1, const u16* __restrict__ b1,
    const u16* __restrict__ w2, const u16* __restrict__ b2,
    const u16* __restrict__ w3, const u16* __restrict__ b3,
    float* __restrict__ out, int M)
{
    __shared__ u16 t_lds[4][16 * 192];

    const int lane = threadIdx.x & 63;
    const int wave = threadIdx.x >> 6;
    const int row0 = (blockIdx.x * 4 + wave) * 16;
    if (row0 >= M) return;
    const int col  = lane & 15;
    const int quad = lane >> 4;
    u16* tl = t_lds[wave];

    f32x4 c0[8];
#pragma unroll
    for (int jt = 0; jt < 8; ++jt) c0[jt] = (f32x4){0.f, 0.f, 0.f, 0.f};
#pragma unroll
    for (int pass = 0; pass < 2; ++pass) {
        const u16* Xp = pass ? X2 : H;
        const u16* Wp = pass ? lrw : llw;
        const u16* xrow = Xp + (size_t)(row0 + col) * 64 + quad * 8;
        const u16* wrow = Wp + (size_t)col * 64 + quad * 8;
#pragma unroll
        for (int kc = 0; kc < 64; kc += 32) {
            short8 a = *(const short8*)(xrow + kc);
#pragma unroll
            for (int jt = 0; jt < 8; ++jt) {
                short8 b = *(const short8*)(wrow + (size_t)jt * 16 * 64 + kc);
                c0[jt] = __builtin_amdgcn_mfma_f32_16x16x32_bf16(a, b, c0[jt], 0, 0, 0);
            }
        }
    }
#pragma unroll
    for (int jt = 0; jt < 8; ++jt) {
        float bias = bf2f(llb[jt * 16 + col]);
#pragma unroll
        for (int r = 0; r < 4; ++r) {
            float v = fmaxf(c0[jt][r] + bias, 0.f);
            int row = quad * 4 + r;
            int k   = jt * 16 + col;
            tl[row * 128 + ((((k >> 3) ^ (row & 7))) << 3) + (k & 7)] = f2bf(v);
        }
    }
    lds_fence();

    short8 af[4];
#pragma unroll
    for (int kc = 0; kc < 4; ++kc) {
        int ch = (kc * 4 + quad) ^ (col & 7);
        af[kc] = *(const short8*)(tl + col * 128 + ch * 8);
    }
    f32x4 c1[12];
#pragma unroll
    for (int jt = 0; jt < 12; ++jt) c1[jt] = (f32x4){0.f, 0.f, 0.f, 0.f};
#pragma unroll
    for (int kc = 0; kc < 4; ++kc) {
#pragma unroll
        for (int jt = 0; jt < 12; ++jt) {
            short8 b = *(const short8*)(w1 + (size_t)(jt * 16 + col) * 128 + kc * 32 + quad * 8);
            c1[jt] = __builtin_amdgcn_mfma_f32_16x16x32_bf16(af[kc], b, c1[jt], 0, 0, 0);
        }
    }
#pragma unroll
    for (int jt = 0; jt < 12; ++jt) {
        float bias = bf2f(b1[jt * 16 + col]);
#pragma unroll
        for (int r = 0; r < 4; ++r) {
            float v = fmaxf(c1[jt][r] + bias, 0.f);
            int row = quad * 4 + r;
            int k   = jt * 16 + col;
            tl[row * 192 + ((((k >> 3) ^ (row & 7))) << 3) + (k & 7)] = f2bf(v);
        }
    }
    lds_fence();

    short8 ag[6];
#pragma unroll
    for (int kc = 0; kc < 6; ++kc) {
        int ch = (kc * 4 + quad) ^ (col & 7);
        ag[kc] = *(const short8*)(tl + col * 192 + ch * 8);
    }
    f32x4 c2[4];
#pragma unroll
    for (int jt = 0; jt < 4; ++jt) c2[jt] = (f32x4){0.f, 0.f, 0.f, 0.f};
#pragma unroll
    for (int kc = 0; kc < 6; ++kc) {
#pragma unroll
        for (int jt = 0; jt < 4; ++jt) {
            short8 b = *(const short8*)(w2 + (size_t)(jt * 16 + col) * 192 + kc * 32 + quad * 8);
            c2[jt] = __builtin_amdgcn_mfma_f32_16x16x32_bf16(ag[kc], b, c2[jt], 0, 0, 0);
        }
    }
#pragma unroll
    for (int jt = 0; jt < 4; ++jt) {
        float bias = bf2f(b2[jt * 16 + col]);
#pragma unroll
        for (int r = 0; r < 4; ++r) {
            float v = fmaxf(c2[jt][r] + bias, 0.f);
            int row = quad * 4 + r;
            int k   = jt * 16 + col;
            tl[row * 64 + ((((k >> 3) ^ (row & 7))) << 3) + (k & 7)] = f2bf(v);
        }
    }
    lds_fence();

    short8 ah[2];
#pragma unroll
    for (int kc = 0; kc < 2; ++kc) {
        int ch = (kc * 4 + quad) ^ (col & 7);
        ah[kc] = *(const short8*)(tl + col * 64 + ch * 8);
    }
    f32x4 c3[4];
#pragma unroll
    for (int jt = 0; jt < 4; ++jt) c3[jt] = (f32x4){0.f, 0.f, 0.f, 0.f};
#pragma unroll
    for (int kc = 0; kc < 2; ++kc) {
#pragma unroll
        for (int jt = 0; jt < 4; ++jt) {
            short8 b = *(const short8*)(w3 + (size_t)(jt * 16 + col) * 64 + kc * 32 + quad * 8);
            c3[jt] = __builtin_amdgcn_mfma_f32_16x16x32_bf16(ah[kc], b, c3[jt], 0, 0, 0);
        }
    }
#pragma unroll
    for (int jt = 0; jt < 4; ++jt) {
        float bias = bf2f(b3[jt * 16 + col]);
#pragma unroll
        for (int r = 0; r < 4; ++r) {
            float v = fmaxf(c3[jt][r] + bias, 0.f);
            out[(size_t)(row0 + quad * 4 + r) * 64 + jt * 16 + col] = v;
        }
    }
}

// ---------------------------------------------------------------------------
extern "C" void kernel_launch(void* const* d_in, const int* in_sizes, int n_in,
                              void* d_out, int out_size, void* d_ws, size_t ws_size,
                              hipStream_t stream)
{
    const u16* x       = (const u16*)d_in[0];
    const int* edge    = (const int*)d_in[1];
    const u16* p1_pw   = (const u16*)d_in[3];
    const u16* p1_pb   = (const u16*)d_in[4];
    const u16* p1_wih  = (const u16*)d_in[5];
    const u16* p1_whh  = (const u16*)d_in[6];
    const u16* p1_bih  = (const u16*)d_in[7];
    const u16* p1_bhh  = (const u16*)d_in[8];
    const u16* p1_llw  = (const u16*)d_in[9];
    const u16* p1_llb  = (const u16*)d_in[10];
    const u16* p1_lrw  = (const u16*)d_in[11];
    const u16* p2_pw   = (const u16*)d_in[12];
    const u16* p2_pb   = (const u16*)d_in[13];
    const u16* p2_wih  = (const u16*)d_in[14];
    const u16* p2_whh  = (const u16*)d_in[15];
    const u16* p2_bih  = (const u16*)d_in[16];
    const u16* p2_bhh  = (const u16*)d_in[17];
    const u16* p2_llw  = (const u16*)d_in[18];
    const u16* p2_llb  = (const u16*)d_in[19];
    const u16* p2_lrw  = (const u16*)d_in[20];
    const u16* lin1w   = (const u16*)d_in[21];
    const u16* lin1b   = (const u16*)d_in[22];
    const u16* lin2w   = (const u16*)d_in[23];
    const u16* lin2b   = (const u16*)d_in[24];
    const u16* lin3w   = (const u16*)d_in[25];
    const u16* lin3b   = (const u16*)d_in[26];
    (void)n_in; (void)ws_size;

    const int N  = in_sizes[0] / 64;     // 50000
    const int E2 = in_sizes[1];          // 1600000
    const int* srcIdx = edge;

    // workspace: scaled weights 128KB @0; xp1 @1MB; H @8MB; Y1 @15MB; xp2 @22MB
    char* w = (char*)d_ws;
    u16* wss   = (u16*)(w);
    u16* xp1   = (u16*)(w + 1u  * 1024 * 1024);
    u16* bufH  = (u16*)(w + 8u  * 1024 * 1024);
    u16* bufY1 = (u16*)(w + 15u * 1024 * 1024);
    u16* xp2   = (u16*)(w + 22u * 1024 * 1024);
    u16* wih1s = wss;
    u16* whh1s = wss + 16384;
    u16* wih2s = wss + 32768;
    u16* whh2s = wss + 49152;

    float* out_h    = (float*)d_out;
    float* out_edge = (float*)d_out + (size_t)N * 64;
    (void)out_size;

    const int gb  = (N + 63) / 64;       // 782 (16-row-per-wave kernels)
    const int gb2 = (N + 127) / 128;     // 391 (32-node-per-wave lstm)
    const int n4 = E2 / 4;
    const int eb = (n4 + 255) / 256;     // 1563

    dim3 block(256);

    hipLaunchKernelGGL(k_pre, dim3(gb + eb + 4), block, 0, stream,
                       x, p1_pw, p1_pb, xp1, N, gb,
                       edge, out_edge, n4, eb,
                       p1_wih, p1_whh, p2_wih, p2_whh, wss);
    hipLaunchKernelGGL(lstm_kernel, dim3(gb2), block, 0, stream,
                       xp1, srcIdx, wih1s, whh1s, p1_bih, p1_bhh, bufH, N);
    hipLaunchKernelGGL(k_mid, dim3(gb), block, 0, stream,
                       bufH, x, p1_llw, p1_llb, p1_lrw, p2_pw, p2_pb, bufY1, xp2, N);
    hipLaunchKernelGGL(lstm_kernel, dim3(gb2), block, 0, stream,
                       xp2, srcIdx, wih2s, whh2s, p2_bih, p2_bhh, bufH, N);
    hipLaunchKernelGGL(k_post, dim3(gb), block, 0, stream,
                       bufH, bufY1, p2_llw, p2_llb, p2_lrw,
                       lin1w, lin1b, lin2w, lin2b, lin3w, lin3b, out_h, N);
}

// Round 8
// 406.743 us; speedup vs baseline: 1.4816x; 1.4816x over previous
//
#include <hip/hip_runtime.h>
#include <hip/hip_bf16.h>

typedef unsigned short u16;
typedef unsigned int u32;
typedef __attribute__((ext_vector_type(8))) short short8;    // 8 bf16 MFMA A/B frag
typedef __attribute__((ext_vector_type(4))) float f32x4;

#define KS1 1.44269504f   // log2(e)
#define KS2 2.88539008f   // 2*log2(e)

__device__ __forceinline__ float bf2f(u16 u) {
    union { u32 i; float f; } v; v.i = ((u32)u) << 16; return v.f;
}
__device__ __forceinline__ u16 f2bf(float f) {            // RNE
    union { float f; u32 i; } v; v.f = f;
    u32 r = v.i + 0x7fffu + ((v.i >> 16) & 1u);
    return (u16)(r >> 16);
}
// pack two f32 -> two bf16 (truncation) in ONE v_perm
__device__ __forceinline__ u32 pack_bf2(float lo, float hi) {
    return __builtin_amdgcn_perm(__float_as_uint(hi), __float_as_uint(lo), 0x07060302u);
}
__device__ __forceinline__ void lds_fence() {
    __asm__ __volatile__("s_waitcnt lgkmcnt(0)" ::: "memory");
}

// ---------------------------------------------------------------------------
// k_pre: [0,gb) xp1 GEMM; [gb,gb+eb) edge cast; [gb+eb,+4) scaled weight copies
// ---------------------------------------------------------------------------
__global__ __launch_bounds__(256) void k_pre(
    const u16* __restrict__ X, const u16* __restrict__ pw, const u16* __restrict__ pb,
    u16* __restrict__ XP, int M, int gb,
    const int* __restrict__ e, float* __restrict__ eout, int n4, int eb,
    const u16* __restrict__ w1i, const u16* __restrict__ w1h,
    const u16* __restrict__ w2i, const u16* __restrict__ w2h,
    u16* __restrict__ wss)
{
    const int bid = blockIdx.x;
    const int tid = threadIdx.x;
    if (bid >= gb + eb) {
        int mi = bid - gb - eb;
        const u16* Wsrc = (mi == 0) ? w1i : (mi == 1) ? w1h : (mi == 2) ? w2i : w2h;
        u16* Wdst = wss + (size_t)mi * 16384;
        for (int idx = tid; idx < 16384; idx += 256) {
            int row = idx >> 6;
            float sc = (row >= 128 && row < 192) ? KS2 : KS1;
            Wdst[idx] = f2bf(bf2f(Wsrc[idx]) * sc);
        }
        return;
    }
    if (bid >= gb) {
        int i = (bid - gb) * 256 + tid;
        if (i < n4) {
            int4 v = *(const int4*)(e + (size_t)i * 4);
            float4 o;
            o.x = (float)v.x; o.y = (float)v.y; o.z = (float)v.z; o.w = (float)v.w;
            *(float4*)(eout + (size_t)i * 4) = o;
        }
        return;
    }
    const int lane = tid & 63;
    const int wave = tid >> 6;
    const int row0 = (bid * 4 + wave) * 16;
    if (row0 >= M) return;
    const int col  = lane & 15;
    const int quad = lane >> 4;

    f32x4 c1[4];
#pragma unroll
    for (int jt = 0; jt < 4; ++jt) c1[jt] = (f32x4){0.f, 0.f, 0.f, 0.f};
    {
        const u16* xrow = X  + (size_t)(row0 + col) * 64 + quad * 8;
        const u16* wrow = pw + (size_t)col * 64 + quad * 8;
#pragma unroll
        for (int kc = 0; kc < 64; kc += 32) {
            short8 a = *(const short8*)(xrow + kc);
#pragma unroll
            for (int jt = 0; jt < 4; ++jt) {
                short8 b = *(const short8*)(wrow + (size_t)jt * 16 * 64 + kc);
                c1[jt] = __builtin_amdgcn_mfma_f32_16x16x32_bf16(a, b, c1[jt], 0, 0, 0);
            }
        }
    }
#pragma unroll
    for (int jt = 0; jt < 4; ++jt) {
        float bias = bf2f(pb[jt * 16 + col]);
#pragma unroll
        for (int r = 0; r < 4; ++r) {
            float v = fmaxf(c1[jt][r] + bias, 0.f);
            XP[(size_t)(row0 + quad * 4 + r) * 64 + jt * 16 + col] = f2bf(v);
        }
    }
}

// ---------------------------------------------------------------------------
// LSTM aggregation v4: weights-in-registers, gate-split across waves.
// Block = 4 waves = 16 nodes. Wave w owns gate tiles jt in {w, w+4, w+8, w+12}
// (one each of i/f/g/o -> nonlinearity for units [w*16,(w+1)*16) is wave-local).
// - A-frags (Wih'+Whh', scaled) live in 64 VGPRs per wave, loaded ONCE.
//   Per-step LDS weight traffic = 0 (round 6's bottleneck).
// - bias' C-operand frags from LDS broadcast (round 7: proven 0 conflicts).
// - h cross-wave exchange: 2x2KB double-buffered LDS, XOR-swizzled 16B chunks,
//   one __syncthreads per step.
// - xp gather prefetched one step (row IS the B-frag).
// NOTE: no waves/EU cap (round 4: cap => catastrophic scratch spill).
// ---------------------------------------------------------------------------
__global__ __launch_bounds__(256) void lstm_kernel(
    const u16* __restrict__ xp,    // [N,64] bf16 (unscaled)
    const int* __restrict__ src,   // [N*16]
    const u16* __restrict__ wihs,  // [256,64] scaled copy
    const u16* __restrict__ whhs,  // [256,64] scaled copy
    const u16* __restrict__ bih, const u16* __restrict__ bhh,  // [256] originals
    u16* __restrict__ Hout,        // [N,64] bf16
    int N)
{
    __shared__ float lds_b[256];        // 1KB bias' (index = gate j)
    __shared__ u16 lds_h[2][16 * 64];   // 2x2KB h double buffer, swizzled

    const int tid  = threadIdx.x;
    const int lane = tid & 63;
    const int w    = tid >> 6;          // wave id = gate-slice id
    const int col  = lane & 15;         // node within block
    const int quad = lane >> 4;

    const int node0 = blockIdx.x * 16;
    if (node0 >= N) return;             // uniform per block
    const int node = node0 + col;

    // bias staging: thread tid -> gate j = tid (scaled)
    {
        int j = tid;
        float sc = (j >= 128 && j < 192) ? KS2 : KS1;
        lds_b[j] = (bf2f(bih[j]) + bf2f(bhh[j])) * sc;
    }

    // persistent weight A-frags: g in {0:i,1:f,2:g,3:o}, jt = w + 4g
    short8 wf[8], hf[8];   // [g*2+kc]
#pragma unroll
    for (int g = 0; g < 4; ++g) {
        int jt = w + 4 * g;
        const u16* wi = wihs + (size_t)(jt * 16 + col) * 64 + quad * 8;
        const u16* wh = whhs + (size_t)(jt * 16 + col) * 64 + quad * 8;
        wf[g * 2 + 0] = *(const short8*)(wi);
        wf[g * 2 + 1] = *(const short8*)(wi + 32);
        hf[g * 2 + 0] = *(const short8*)(wh);
        hf[g * 2 + 1] = *(const short8*)(wh + 32);
    }

    // node indices: lane (col,quad) covers steps quad*4 .. quad*4+3
    int4 sidx = *(const int4*)(src + (size_t)node * 16 + quad * 4);

    // t=0 xp prefetch (B-frag direct)
    short8 xb0, xb1;
    {
        int s0 = __shfl(sidx.x, col, 64);
        const u16* px = xp + (size_t)s0 * 64 + quad * 8;
        xb0 = *(const short8*)px;
        xb1 = *(const short8*)(px + 32);
    }

    short8 hb0 = (short8){0,0,0,0,0,0,0,0};
    short8 hb1 = (short8){0,0,0,0,0,0,0,0};
    float c_[4];
#pragma unroll
    for (int i = 0; i < 4; ++i) c_[i] = 0.f;

    __syncthreads();   // bias visible

    const int xsw = col & 7;   // XOR swizzle key (row = col for both write+read)

#pragma unroll 1
    for (int t = 0; t < 16; ++t) {
        // 1) Wih GEMM, bias as C operand (LDS broadcast frag)
        f32x4 acc[4];
#pragma unroll
        for (int g = 0; g < 4; ++g) {
            f32x4 bc = *(const f32x4*)(lds_b + (w + 4 * g) * 16 + quad * 4);
            acc[g] = __builtin_amdgcn_mfma_f32_16x16x32_bf16(wf[g * 2 + 0], xb0, bc, 0, 0, 0);
            acc[g] = __builtin_amdgcn_mfma_f32_16x16x32_bf16(wf[g * 2 + 1], xb1, acc[g], 0, 0, 0);
        }
        // 2) prefetch next step's xp row
        if (t < 15) {
            int tn = t + 1;
            int cv = (tn & 2) ? ((tn & 1) ? sidx.w : sidx.z)
                              : ((tn & 1) ? sidx.y : sidx.x);
            int sn = __shfl(cv, ((tn >> 2) << 4) + col, 64);
            const u16* px = xp + (size_t)sn * 64 + quad * 8;
            xb0 = *(const short8*)px;
            xb1 = *(const short8*)(px + 32);
        }
        // 3) Whh GEMM
        if (t > 0) {
#pragma unroll
            for (int g = 0; g < 4; ++g) {
                acc[g] = __builtin_amdgcn_mfma_f32_16x16x32_bf16(hf[g * 2 + 0], hb0, acc[g], 0, 0, 0);
                acc[g] = __builtin_amdgcn_mfma_f32_16x16x32_bf16(hf[g * 2 + 1], hb1, acc[g], 0, 0, 0);
            }
        }
        // 4) nonlinearity (scaled domain), units w*16 + quad*4 + r
        float hv[4];
#pragma unroll
        for (int r = 0; r < 4; ++r) {
            float iv = acc[0][r];
            float fv = acc[1][r];
            float gv = acc[2][r];
            float ov = acc[3][r];
            float e_i = __builtin_amdgcn_exp2f(-iv);
            float e_f = __builtin_amdgcn_exp2f(-fv);
            float e_g = __builtin_amdgcn_exp2f(gv);
            float sf  = __builtin_amdgcn_rcpf(1.0f + e_f);
            float rig = __builtin_amdgcn_rcpf((1.0f + e_i) * (1.0f + e_g));
            float tt  = __builtin_fmaf(e_g, KS2, -KS2);
            float cn  = __builtin_fmaf(sf, c_[r], tt * rig);
            c_[r] = cn;
            float e_c = __builtin_amdgcn_exp2f(cn);
            float e_o = __builtin_amdgcn_exp2f(-ov);
            float roc = __builtin_amdgcn_rcpf((1.0f + e_o) * (1.0f + e_c));
            hv[r] = (e_c - 1.0f) * roc;
        }
        u32 w0 = pack_bf2(hv[0], hv[1]);
        u32 w1 = pack_bf2(hv[2], hv[3]);

        if (t == 15) {
            uint2 o; o.x = w0; o.y = w1;
            *(uint2*)(Hout + (size_t)node * 64 + w * 16 + quad * 4) = o;
        } else {
            // 5) write h slice to swizzled double buffer:
            //    dims d = w*16+quad*4+0..3 -> chunk ch = 2w + (quad>>1),
            //    u16 slot = col*64 + (ch^xsw)*8 + (quad&1)*4
            u16* hb = lds_h[t & 1];
            int ch = 2 * w + (quad >> 1);
            *(uint2*)(hb + col * 64 + ((ch ^ xsw) << 3) + ((quad & 1) << 2)) = (uint2){w0, w1};
            __syncthreads();
            // 6) read next-step B-frags: kc0 dims quad*8.. (ch=quad), kc1 dims 32+quad*8 (ch=4+quad)
            hb0 = *(const short8*)(hb + col * 64 + (((quad + 0) ^ xsw) << 3));
            hb1 = *(const short8*)(hb + col * 64 + (((quad + 4) ^ xsw) << 3));
        }
    }
}

// ---------------------------------------------------------------------------
// k_mid: Y1 = relu(H@llw^T + X2@lrw^T + llb) -> global + LDS
//        xp2 = relu(Y1@pw^T + pb)            -> global
// ---------------------------------------------------------------------------
__global__ __launch_bounds__(256) void k_mid(
    const u16* __restrict__ H, const u16* __restrict__ X2,
    const u16* __restrict__ llw, const u16* __restrict__ llb,
    const u16* __restrict__ lrw,
    const u16* __restrict__ pw, const u16* __restrict__ pb,
    u16* __restrict__ Y1, u16* __restrict__ XP2, int M)
{
    __shared__ u16 t_lds[4][16 * 64];

    const int lane = threadIdx.x & 63;
    const int wave = threadIdx.x >> 6;
    const int row0 = (blockIdx.x * 4 + wave) * 16;
    if (row0 >= M) return;
    const int col  = lane & 15;
    const int quad = lane >> 4;
    u16* tl = t_lds[wave];

    f32x4 c0[4];
#pragma unroll
    for (int jt = 0; jt < 4; ++jt) c0[jt] = (f32x4){0.f, 0.f, 0.f, 0.f};
#pragma unroll
    for (int pass = 0; pass < 2; ++pass) {
        const u16* Xp = pass ? X2 : H;
        const u16* Wp = pass ? lrw : llw;
        const u16* xrow = Xp + (size_t)(row0 + col) * 64 + quad * 8;
        const u16* wrow = Wp + (size_t)col * 64 + quad * 8;
#pragma unroll
        for (int kc = 0; kc < 64; kc += 32) {
            short8 a = *(const short8*)(xrow + kc);
#pragma unroll
            for (int jt = 0; jt < 4; ++jt) {
                short8 b = *(const short8*)(wrow + (size_t)jt * 16 * 64 + kc);
                c0[jt] = __builtin_amdgcn_mfma_f32_16x16x32_bf16(a, b, c0[jt], 0, 0, 0);
            }
        }
    }
#pragma unroll
    for (int jt = 0; jt < 4; ++jt) {
        float bias = bf2f(llb[jt * 16 + col]);
#pragma unroll
        for (int r = 0; r < 4; ++r) {
            float v = fmaxf(c0[jt][r] + bias, 0.f);
            u16 vb = f2bf(v);
            int row = quad * 4 + r;
            int k   = jt * 16 + col;
            Y1[(size_t)(row0 + row) * 64 + k] = vb;
            tl[row * 64 + ((((k >> 3) ^ (row & 7))) << 3) + (k & 7)] = vb;
        }
    }
    lds_fence();

    short8 a0f, a1f;
    {
        int c0i = (0 * 4 + quad) ^ (col & 7);
        int c1i = (1 * 4 + quad) ^ (col & 7);
        a0f = *(const short8*)(tl + col * 64 + c0i * 8);
        a1f = *(const short8*)(tl + col * 64 + c1i * 8);
    }
    f32x4 c1[4];
#pragma unroll
    for (int jt = 0; jt < 4; ++jt) c1[jt] = (f32x4){0.f, 0.f, 0.f, 0.f};
    {
        const u16* wrow = pw + (size_t)col * 64 + quad * 8;
#pragma unroll
        for (int jt = 0; jt < 4; ++jt) {
            short8 b0 = *(const short8*)(wrow + (size_t)jt * 16 * 64);
            c1[jt] = __builtin_amdgcn_mfma_f32_16x16x32_bf16(a0f, b0, c1[jt], 0, 0, 0);
            short8 b1 = *(const short8*)(wrow + (size_t)jt * 16 * 64 + 32);
            c1[jt] = __builtin_amdgcn_mfma_f32_16x16x32_bf16(a1f, b1, c1[jt], 0, 0, 0);
        }
    }
#pragma unroll
    for (int jt = 0; jt < 4; ++jt) {
        float bias = bf2f(pb[jt * 16 + col]);
#pragma unroll
        for (int r = 0; r < 4; ++r) {
            float v = fmaxf(c1[jt][r] + bias, 0.f);
            XP2[(size_t)(row0 + quad * 4 + r) * 64 + jt * 16 + col] = f2bf(v);
        }
    }
}

// ---------------------------------------------------------------------------
// k_post: Y2[128] (LDS) -> T1[192] -> T2[64] -> out[64] f32
// ---------------------------------------------------------------------------
__global__ __launch_bounds__(256) void k_post(
    const u16* __restrict__ H, const u16* __restrict__ X2,
    const u16* __restrict__ llw, const u16* __restrict__ llb,
    const u16* __restrict__ lrw,
    const u16* __restrict__ w1, const u16* __restrict__ b1,
    const u16* __restrict__ w2, const u16* __restrict__ b2,
    const u16* __restrict__ w3, const u16* __restrict__ b3,
    float* __restrict__ out, int M)
{
    __shared__ u16 t_lds[4][16 * 192];

    const int lane = threadIdx.x & 63;
    const int wave = threadIdx.x >> 6;
    const int row0 = (blockIdx.x * 4 + wave) * 16;
    if (row0 >= M) return;
    const int col  = lane & 15;
    const int quad = lane >> 4;
    u16* tl = t_lds[wave];

    f32x4 c0[8];
#pragma unroll
    for (int jt = 0; jt < 8; ++jt) c0[jt] = (f32x4){0.f, 0.f, 0.f, 0.f};
#pragma unroll
    for (int pass = 0; pass < 2; ++pass) {
        const u16* Xp = pass ? X2 : H;
        const u16* Wp = pass ? lrw : llw;
        const u16* xrow = Xp + (size_t)(row0 + col) * 64 + quad * 8;
        const u16* wrow = Wp + (size_t)col * 64 + quad * 8;
#pragma unroll
        for (int kc = 0; kc < 64; kc += 32) {
            short8 a = *(const short8*)(xrow + kc);
#pragma unroll
            for (int jt = 0; jt < 8; ++jt) {
                short8 b = *(const short8*)(wrow + (size_t)jt * 16 * 64 + kc);
                c0[jt] = __builtin_amdgcn_mfma_f32_16x16x32_bf16(a, b, c0[jt], 0, 0, 0);
            }
        }
    }
#pragma unroll
    for (int jt = 0; jt < 8; ++jt) {
        float bias = bf2f(llb[jt * 16 + col]);
#pragma unroll
        for (int r = 0; r < 4; ++r) {
            float v = fmaxf(c0[jt][r] + bias, 0.f);
            int row = quad * 4 + r;
            int k   = jt * 16 + col;
            tl[row * 128 + ((((k >> 3) ^ (row & 7))) << 3) + (k & 7)] = f2bf(v);
        }
    }
    lds_fence();

    short8 af[4];
#pragma unroll
    for (int kc = 0; kc < 4; ++kc) {
        int ch = (kc * 4 + quad) ^ (col & 7);
        af[kc] = *(const short8*)(tl + col * 128 + ch * 8);
    }
    f32x4 c1[12];
#pragma unroll
    for (int jt = 0; jt < 12; ++jt) c1[jt] = (f32x4){0.f, 0.f, 0.f, 0.f};
#pragma unroll
    for (int kc = 0; kc < 4; ++kc) {
#pragma unroll
        for (int jt = 0; jt < 12; ++jt) {
            short8 b = *(const short8*)(w1 + (size_t)(jt * 16 + col) * 128 + kc * 32 + quad * 8);
            c1[jt] = __builtin_amdgcn_mfma_f32_16x16x32_bf16(af[kc], b, c1[jt], 0, 0, 0);
        }
    }
#pragma unroll
    for (int jt = 0; jt < 12; ++jt) {
        float bias = bf2f(b1[jt * 16 + col]);
#pragma unroll
        for (int r = 0; r < 4; ++r) {
            float v = fmaxf(c1[jt][r] + bias, 0.f);
            int row = quad * 4 + r;
            int k   = jt * 16 + col;
            tl[row * 192 + ((((k >> 3) ^ (row & 7))) << 3) + (k & 7)] = f2bf(v);
        }
    }
    lds_fence();

    short8 ag[6];
#pragma unroll
    for (int kc = 0; kc < 6; ++kc) {
        int ch = (kc * 4 + quad) ^ (col & 7);
        ag[kc] = *(const short8*)(tl + col * 192 + ch * 8);
    }
    f32x4 c2[4];
#pragma unroll
    for (int jt = 0; jt < 4; ++jt) c2[jt] = (f32x4){0.f, 0.f, 0.f, 0.f};
#pragma unroll
    for (int kc = 0; kc < 6; ++kc) {
#pragma unroll
        for (int jt = 0; jt < 4; ++jt) {
            short8 b = *(const short8*)(w2 + (size_t)(jt * 16 + col) * 192 + kc * 32 + quad * 8);
            c2[jt] = __builtin_amdgcn_mfma_f32_16x16x32_bf16(ag[kc], b, c2[jt], 0, 0, 0);
        }
    }
#pragma unroll
    for (int jt = 0; jt < 4; ++jt) {
        float bias = bf2f(b2[jt * 16 + col]);
#pragma unroll
        for (int r = 0; r < 4; ++r) {
            float v = fmaxf(c2[jt][r] + bias, 0.f);
            int row = quad * 4 + r;
            int k   = jt * 16 + col;
            tl[row * 64 + ((((k >> 3) ^ (row & 7))) << 3) + (k & 7)] = f2bf(v);
        }
    }
    lds_fence();

    short8 ah[2];
#pragma unroll
    for (int kc = 0; kc < 2; ++kc) {
        int ch = (kc * 4 + quad) ^ (col & 7);
        ah[kc] = *(const short8*)(tl + col * 64 + ch * 8);
    }
    f32x4 c3[4];
#pragma unroll
    for (int jt = 0; jt < 4; ++jt) c3[jt] = (f32x4){0.f, 0.f, 0.f, 0.f};
#pragma unroll
    for (int kc = 0; kc < 2; ++kc) {
#pragma unroll
        for (int jt = 0; jt < 4; ++jt) {
            short8 b = *(const short8*)(w3 + (size_t)(jt * 16 + col) * 64 + kc * 32 + quad * 8);
            c3[jt] = __builtin_amdgcn_mfma_f32_16x16x32_bf16(ah[kc], b, c3[jt], 0, 0, 0);
        }
    }
#pragma unroll
    for (int jt = 0; jt < 4; ++jt) {
        float bias = bf2f(b3[jt * 16 + col]);
#pragma unroll
        for (int r = 0; r < 4; ++r) {
            float v = fmaxf(c3[jt][r] + bias, 0.f);
            out[(size_t)(row0 + quad * 4 + r) * 64 + jt * 16 + col] = v;
        }
    }
}

// ---------------------------------------------------------------------------
extern "C" void kernel_launch(void* const* d_in, const int* in_sizes, int n_in,
                              void* d_out, int out_size, void* d_ws, size_t ws_size,
                              hipStream_t stream)
{
    const u16* x       = (const u16*)d_in[0];
    const int* edge    = (const int*)d_in[1];
    const u16* p1_pw   = (const u16*)d_in[3];
    const u16* p1_pb   = (const u16*)d_in[4];
    const u16* p1_wih  = (const u16*)d_in[5];
    const u16* p1_whh  = (const u16*)d_in[6];
    const u16* p1_bih  = (const u16*)d_in[7];
    const u16* p1_bhh  = (const u16*)d_in[8];
    const u16* p1_llw  = (const u16*)d_in[9];
    const u16* p1_llb  = (const u16*)d_in[10];
    const u16* p1_lrw  = (const u16*)d_in[11];
    const u16* p2_pw   = (const u16*)d_in[12];
    const u16* p2_pb   = (const u16*)d_in[13];
    const u16* p2_wih  = (const u16*)d_in[14];
    const u16* p2_whh  = (const u16*)d_in[15];
    const u16* p2_bih  = (const u16*)d_in[16];
    const u16* p2_bhh  = (const u16*)d_in[17];
    const u16* p2_llw  = (const u16*)d_in[18];
    const u16* p2_llb  = (const u16*)d_in[19];
    const u16* p2_lrw  = (const u16*)d_in[20];
    const u16* lin1w   = (const u16*)d_in[21];
    const u16* lin1b   = (const u16*)d_in[22];
    const u16* lin2w   = (const u16*)d_in[23];
    const u16* lin2b   = (const u16*)d_in[24];
    const u16* lin3w   = (const u16*)d_in[25];
    const u16* lin3b   = (const u16*)d_in[26];
    (void)n_in; (void)ws_size;

    const int N  = in_sizes[0] / 64;     // 50000
    const int E2 = in_sizes[1];          // 1600000
    const int* srcIdx = edge;

    // workspace: scaled weights 128KB @0; xp1 @1MB; H @8MB; Y1 @15MB; xp2 @22MB
    char* w = (char*)d_ws;
    u16* wss   = (u16*)(w);
    u16* xp1   = (u16*)(w + 1u  * 1024 * 1024);
    u16* bufH  = (u16*)(w + 8u  * 1024 * 1024);
    u16* bufY1 = (u16*)(w + 15u * 1024 * 1024);
    u16* xp2   = (u16*)(w + 22u * 1024 * 1024);
    u16* wih1s = wss;
    u16* whh1s = wss + 16384;
    u16* wih2s = wss + 32768;
    u16* whh2s = wss + 49152;

    float* out_h    = (float*)d_out;
    float* out_edge = (float*)d_out + (size_t)N * 64;
    (void)out_size;

    const int gb  = (N + 63) / 64;       // 782 (16-row-per-wave kernels)
    const int gbl = (N + 15) / 16;       // 3125 (16-node-per-block lstm)
    const int n4 = E2 / 4;
    const int eb = (n4 + 255) / 256;     // 1563

    dim3 block(256);

    hipLaunchKernelGGL(k_pre, dim3(gb + eb + 4), block, 0, stream,
                       x, p1_pw, p1_pb, xp1, N, gb,
                       edge, out_edge, n4, eb,
                       p1_wih, p1_whh, p2_wih, p2_whh, wss);
    hipLaunchKernelGGL(lstm_kernel, dim3(gbl), block, 0, stream,
                       xp1, srcIdx, wih1s, whh1s, p1_bih, p1_bhh, bufH, N);
    hipLaunchKernelGGL(k_mid, dim3(gb), block, 0, stream,
                       bufH, x, p1_llw, p1_llb, p1_lrw, p2_pw, p2_pb, bufY1, xp2, N);
    hipLaunchKernelGGL(lstm_kernel, dim3(gbl), block, 0, stream,
                       xp2, srcIdx, wih2s, whh2s, p2_bih, p2_bhh, bufH, N);
    hipLaunchKernelGGL(k_post, dim3(gb), block, 0, stream,
                       bufH, bufY1, p2_llw, p2_llb, p2_lrw,
                       lin1w, lin1b, lin2w, lin2b, lin3w, lin3b, out_h, N);
}

// Round 9
// 367.243 us; speedup vs baseline: 1.6409x; 1.1076x over previous
//
#include <hip/hip_runtime.h>
#include <hip/hip_bf16.h>

typedef unsigned short u16;
typedef unsigned int u32;
typedef __attribute__((ext_vector_type(8))) short short8;    // 8 bf16 MFMA A/B frag
typedef __attribute__((ext_vector_type(4))) float f32x4;

#define KS1 1.44269504f   // log2(e)
#define KS2 2.88539008f   // 2*log2(e)

__device__ __forceinline__ float bf2f(u16 u) {
    union { u32 i; float f; } v; v.i = ((u32)u) << 16; return v.f;
}
__device__ __forceinline__ u16 f2bf(float f) {            // RNE
    union { float f; u32 i; } v; v.f = f;
    u32 r = v.i + 0x7fffu + ((v.i >> 16) & 1u);
    return (u16)(r >> 16);
}
// pack two f32 -> two bf16 (truncation) in ONE v_perm (h state only)
__device__ __forceinline__ u32 pack_bf2(float lo, float hi) {
    return __builtin_amdgcn_perm(__float_as_uint(hi), __float_as_uint(lo), 0x07060302u);
}
// relu + RNE pack (epilogue intermediates)
__device__ __forceinline__ u32 pack_relu(float a, float b) {
    return (u32)f2bf(fmaxf(a, 0.f)) | ((u32)f2bf(fmaxf(b, 0.f)) << 16);
}
__device__ __forceinline__ f32x4 bias4(const u16* b) {
    uint2 u = *(const uint2*)b;
    f32x4 r;
    r[0] = bf2f((u16)(u.x & 0xffffu)); r[1] = bf2f((u16)(u.x >> 16));
    r[2] = bf2f((u16)(u.y & 0xffffu)); r[3] = bf2f((u16)(u.y >> 16));
    return r;
}
// XOR-swizzled exchange buffer (proven bank-free: 2-way max).
// write tile jt (dims jt*16+quad*4+r, node col), D2 = row stride in u16
__device__ __forceinline__ void xwrite(u16* buf, int D2, int col, int quad, int jt, u32 w0, u32 w1) {
    int ch = jt * 2 + (quad >> 1);
    *(uint2*)(buf + col * D2 + ((ch ^ (col & 7)) << 3) + ((quad & 1) << 2)) = (uint2){w0, w1};
}
// read B-frag chunk kc: elements kc*32 + quad*8 .. of row col
__device__ __forceinline__ short8 xread(const u16* buf, int D2, int col, int quad, int kc) {
    return *(const short8*)(buf + col * D2 + (((kc * 4 + quad) ^ (col & 7)) << 3));
}
#define MFMA16 __builtin_amdgcn_mfma_f32_16x16x32_bf16

// ---------------------------------------------------------------------------
// k_pre: [0,gb) xp1 GEMM; [gb,gb+eb) edge cast; [gb+eb,+4) scaled weight copies
// ---------------------------------------------------------------------------
__global__ __launch_bounds__(256) void k_pre(
    const u16* __restrict__ X, const u16* __restrict__ pw, const u16* __restrict__ pb,
    u16* __restrict__ XP, int M, int gb,
    const int* __restrict__ e, float* __restrict__ eout, int n4, int eb,
    const u16* __restrict__ w1i, const u16* __restrict__ w1h,
    const u16* __restrict__ w2i, const u16* __restrict__ w2h,
    u16* __restrict__ wss)
{
    const int bid = blockIdx.x;
    const int tid = threadIdx.x;
    if (bid >= gb + eb) {
        int mi = bid - gb - eb;
        const u16* Wsrc = (mi == 0) ? w1i : (mi == 1) ? w1h : (mi == 2) ? w2i : w2h;
        u16* Wdst = wss + (size_t)mi * 16384;
        for (int idx = tid; idx < 16384; idx += 256) {
            int row = idx >> 6;
            float sc = (row >= 128 && row < 192) ? KS2 : KS1;
            Wdst[idx] = f2bf(bf2f(Wsrc[idx]) * sc);
        }
        return;
    }
    if (bid >= gb) {
        int i = (bid - gb) * 256 + tid;
        if (i < n4) {
            int4 v = *(const int4*)(e + (size_t)i * 4);
            float4 o;
            o.x = (float)v.x; o.y = (float)v.y; o.z = (float)v.z; o.w = (float)v.w;
            *(float4*)(eout + (size_t)i * 4) = o;
        }
        return;
    }
    const int lane = tid & 63;
    const int wave = tid >> 6;
    const int row0 = (bid * 4 + wave) * 16;
    if (row0 >= M) return;
    const int col  = lane & 15;
    const int quad = lane >> 4;

    f32x4 c1[4];
#pragma unroll
    for (int jt = 0; jt < 4; ++jt) c1[jt] = (f32x4){0.f, 0.f, 0.f, 0.f};
    {
        const u16* xrow = X  + (size_t)(row0 + col) * 64 + quad * 8;
        const u16* wrow = pw + (size_t)col * 64 + quad * 8;
#pragma unroll
        for (int kc = 0; kc < 64; kc += 32) {
            short8 a = *(const short8*)(xrow + kc);
#pragma unroll
            for (int jt = 0; jt < 4; ++jt) {
                short8 b = *(const short8*)(wrow + (size_t)jt * 16 * 64 + kc);
                c1[jt] = MFMA16(a, b, c1[jt], 0, 0, 0);
            }
        }
    }
#pragma unroll
    for (int jt = 0; jt < 4; ++jt) {
        float bias = bf2f(pb[jt * 16 + col]);
#pragma unroll
        for (int r = 0; r < 4; ++r) {
            float v = fmaxf(c1[jt][r] + bias, 0.f);
            XP[(size_t)(row0 + quad * 4 + r) * 64 + jt * 16 + col] = f2bf(v);
        }
    }
}

// ===========================================================================
// LSTM core (round 8's weights-in-registers design, exchange on ALL 16 steps)
// + fused epilogues. Block = 4 waves = 16 nodes; wave w owns gate tiles
// {w, w+4, w+8, w+12}; Wih'/Whh' frags in 64 VGPRs; bias' C-operand from LDS.
// After the loop, hb0/hb1 = H B-frags -> feed the per-block epilogue GEMMs.
// ===========================================================================

#define LSTM_CORE_LOOP                                                         \
    short8 hb0 = (short8){0,0,0,0,0,0,0,0};                                    \
    short8 hb1 = (short8){0,0,0,0,0,0,0,0};                                    \
    float c_[4];                                                               \
    _Pragma("unroll") for (int i = 0; i < 4; ++i) c_[i] = 0.f;                 \
    __syncthreads();                                                           \
    const int xsw = col & 7;                                                   \
    _Pragma("unroll 1") for (int t = 0; t < 16; ++t) {                         \
        f32x4 acc[4];                                                          \
        _Pragma("unroll") for (int g = 0; g < 4; ++g) {                        \
            f32x4 bc = *(const f32x4*)(lds_b + (w + 4 * g) * 16 + quad * 4);   \
            acc[g] = MFMA16(wf[g * 2 + 0], xb0, bc, 0, 0, 0);                  \
            acc[g] = MFMA16(wf[g * 2 + 1], xb1, acc[g], 0, 0, 0);              \
        }                                                                      \
        if (t < 15) {                                                          \
            int tn = t + 1;                                                    \
            int cv = (tn & 2) ? ((tn & 1) ? sidx.w : sidx.z)                   \
                              : ((tn & 1) ? sidx.y : sidx.x);                  \
            int sn = __shfl(cv, ((tn >> 2) << 4) + col, 64);                   \
            const u16* px = xp + (size_t)sn * 64 + quad * 8;                   \
            xb0 = *(const short8*)px;                                          \
            xb1 = *(const short8*)(px + 32);                                   \
        }                                                                      \
        if (t > 0) {                                                           \
            _Pragma("unroll") for (int g = 0; g < 4; ++g) {                    \
                acc[g] = MFMA16(hf[g * 2 + 0], hb0, acc[g], 0, 0, 0);          \
                acc[g] = MFMA16(hf[g * 2 + 1], hb1, acc[g], 0, 0, 0);          \
            }                                                                  \
        }                                                                      \
        float hv[4];                                                           \
        _Pragma("unroll") for (int r = 0; r < 4; ++r) {                        \
            float iv = acc[0][r], fv = acc[1][r], gv = acc[2][r], ov = acc[3][r]; \
            float e_i = __builtin_amdgcn_exp2f(-iv);                           \
            float e_f = __builtin_amdgcn_exp2f(-fv);                           \
            float e_g = __builtin_amdgcn_exp2f(gv);                            \
            float sf  = __builtin_amdgcn_rcpf(1.0f + e_f);                     \
            float rig = __builtin_amdgcn_rcpf((1.0f + e_i) * (1.0f + e_g));    \
            float tt  = __builtin_fmaf(e_g, KS2, -KS2);                        \
            float cn  = __builtin_fmaf(sf, c_[r], tt * rig);                   \
            c_[r] = cn;                                                        \
            float e_c = __builtin_amdgcn_exp2f(cn);                            \
            float e_o = __builtin_amdgcn_exp2f(-ov);                           \
            float roc = __builtin_amdgcn_rcpf((1.0f + e_o) * (1.0f + e_c));    \
            hv[r] = (e_c - 1.0f) * roc;                                        \
        }                                                                      \
        u32 hw0 = pack_bf2(hv[0], hv[1]);                                      \
        u32 hw1 = pack_bf2(hv[2], hv[3]);                                      \
        u16* hbuf = lds_h[t & 1];                                              \
        xwrite(hbuf, 64, col, quad, w, hw0, hw1);                              \
        __syncthreads();                                                       \
        hb0 = xread(hbuf, 64, col, quad, 0);                                   \
        hb1 = xread(hbuf, 64, col, quad, 1);                                   \
    }

#define LSTM_PROLOGUE                                                          \
    const int tid  = threadIdx.x;                                              \
    const int lane = tid & 63;                                                 \
    const int w    = tid >> 6;                                                 \
    const int col  = lane & 15;                                                \
    const int quad = lane >> 4;                                                \
    const int node0 = blockIdx.x * 16;                                         \
    if (node0 >= N) return;                                                    \
    {                                                                          \
        int j = tid;                                                           \
        float sc = (j >= 128 && j < 192) ? KS2 : KS1;                          \
        lds_b[j] = (bf2f(bih[j]) + bf2f(bhh[j])) * sc;                         \
    }                                                                          \
    short8 wf[8], hf[8];                                                       \
    _Pragma("unroll") for (int g = 0; g < 4; ++g) {                            \
        int jt = w + 4 * g;                                                    \
        const u16* wi = wihs + (size_t)(jt * 16 + col) * 64 + quad * 8;        \
        const u16* wh = whhs + (size_t)(jt * 16 + col) * 64 + quad * 8;        \
        wf[g * 2 + 0] = *(const short8*)(wi);                                  \
        wf[g * 2 + 1] = *(const short8*)(wi + 32);                             \
        hf[g * 2 + 0] = *(const short8*)(wh);                                  \
        hf[g * 2 + 1] = *(const short8*)(wh + 32);                             \
    }                                                                          \
    int4 sidx = *(const int4*)(src + (size_t)(node0 + col) * 16 + quad * 4);   \
    short8 xb0, xb1;                                                           \
    {                                                                          \
        int s0 = __shfl(sidx.x, col, 64);                                      \
        const u16* px = xp + (size_t)s0 * 64 + quad * 8;                       \
        xb0 = *(const short8*)px;                                              \
        xb1 = *(const short8*)(px + 32);                                       \
    }

// ---------------------------------------------------------------------------
// lstm_mid: layer-1 LSTM + fused k_mid epilogue:
//   Y1 = relu(ll@H + lr@x + llb) -> global + exchange;  xp2 = relu(pw@Y1 + pb)
// ---------------------------------------------------------------------------
__global__ __launch_bounds__(256) void lstm_mid(
    const u16* __restrict__ xp, const int* __restrict__ src,
    const u16* __restrict__ wihs, const u16* __restrict__ whhs,
    const u16* __restrict__ bih, const u16* __restrict__ bhh,
    const u16* __restrict__ X,                                   // root x [N,64]
    const u16* __restrict__ llw, const u16* __restrict__ llb,
    const u16* __restrict__ lrw,
    const u16* __restrict__ pw, const u16* __restrict__ pb,
    u16* __restrict__ Y1, u16* __restrict__ XP2, int N)
{
    __shared__ float lds_b[256];        // 1KB scaled bias'
    __shared__ u16 lds_h[2][16 * 64];   // 4KB h double buffer
    __shared__ u16 bufY[16 * 64];       // 2KB Y1 exchange

    LSTM_PROLOGUE
    LSTM_CORE_LOOP

    // ---- epilogue (fused k_mid): hb0/hb1 = H B-frags ----
    {
        // Y1^T tile jt=w
        const u16* wr = llw + (size_t)(w * 16 + col) * 64 + quad * 8;
        f32x4 acc = bias4(llb + w * 16 + quad * 4);
        acc = MFMA16(*(const short8*)(wr),      hb0, acc, 0, 0, 0);
        acc = MFMA16(*(const short8*)(wr + 32), hb1, acc, 0, 0, 0);
        const u16* xr = X + (size_t)(node0 + col) * 64 + quad * 8;
        short8 rx0 = *(const short8*)xr;
        short8 rx1 = *(const short8*)(xr + 32);
        const u16* wr2 = lrw + (size_t)(w * 16 + col) * 64 + quad * 8;
        acc = MFMA16(*(const short8*)(wr2),      rx0, acc, 0, 0, 0);
        acc = MFMA16(*(const short8*)(wr2 + 32), rx1, acc, 0, 0, 0);
        u32 y0 = pack_relu(acc[0], acc[1]);
        u32 y1 = pack_relu(acc[2], acc[3]);
        *(uint2*)(Y1 + (size_t)(node0 + col) * 64 + w * 16 + quad * 4) = (uint2){y0, y1};
        xwrite(bufY, 64, col, quad, w, y0, y1);
        __syncthreads();
        short8 yb0 = xread(bufY, 64, col, quad, 0);
        short8 yb1 = xread(bufY, 64, col, quad, 1);
        // xp2^T tile jt=w
        const u16* wp = pw + (size_t)(w * 16 + col) * 64 + quad * 8;
        f32x4 a2 = bias4(pb + w * 16 + quad * 4);
        a2 = MFMA16(*(const short8*)(wp),      yb0, a2, 0, 0, 0);
        a2 = MFMA16(*(const short8*)(wp + 32), yb1, a2, 0, 0, 0);
        *(uint2*)(XP2 + (size_t)(node0 + col) * 64 + w * 16 + quad * 4) =
            (uint2){pack_relu(a2[0], a2[1]), pack_relu(a2[2], a2[3])};
    }
}

// ---------------------------------------------------------------------------
// lstm_post: layer-2 LSTM + fused k_post epilogue:
//   Y2[128] = relu(ll2@H + lr2@Y1 + llb2); T1[192]; T2[64]; out[64] f32
// ---------------------------------------------------------------------------
__global__ __launch_bounds__(256) void lstm_post(
    const u16* __restrict__ xp, const int* __restrict__ src,
    const u16* __restrict__ wihs, const u16* __restrict__ whhs,
    const u16* __restrict__ bih, const u16* __restrict__ bhh,
    const u16* __restrict__ Y1,                                  // [N,64]
    const u16* __restrict__ llw2, const u16* __restrict__ llb2,
    const u16* __restrict__ lrw2,                                // [128,64],[128],[128,64]
    const u16* __restrict__ w1m, const u16* __restrict__ b1m,    // [192,128],[192]
    const u16* __restrict__ w2m, const u16* __restrict__ b2m,    // [64,192],[64]
    const u16* __restrict__ w3m, const u16* __restrict__ b3m,    // [64,64],[64]
    float* __restrict__ outp, int N)
{
    __shared__ float lds_b[256];        // 1KB scaled bias'
    __shared__ u16 lds_h[2][16 * 64];   // 4KB h double buffer
    __shared__ u16 bufA[16 * 128];      // 4KB Y2 exchange (reused for T2 @ stride 64)
    __shared__ u16 bufB[16 * 192];      // 6KB T1 exchange

    LSTM_PROLOGUE
    LSTM_CORE_LOOP

    // ---- epilogue (fused k_post) ----
    {
        const u16* y1r = Y1 + (size_t)(node0 + col) * 64 + quad * 8;
        short8 ry0 = *(const short8*)y1r;
        short8 ry1 = *(const short8*)(y1r + 32);
        // Y2 tiles jt = 2w, 2w+1
#pragma unroll
        for (int ti = 0; ti < 2; ++ti) {
            int jt = 2 * w + ti;
            const u16* wr = llw2 + (size_t)(jt * 16 + col) * 64 + quad * 8;
            f32x4 acc = bias4(llb2 + jt * 16 + quad * 4);
            acc = MFMA16(*(const short8*)(wr),      hb0, acc, 0, 0, 0);
            acc = MFMA16(*(const short8*)(wr + 32), hb1, acc, 0, 0, 0);
            const u16* wr2 = lrw2 + (size_t)(jt * 16 + col) * 64 + quad * 8;
            acc = MFMA16(*(const short8*)(wr2),      ry0, acc, 0, 0, 0);
            acc = MFMA16(*(const short8*)(wr2 + 32), ry1, acc, 0, 0, 0);
            xwrite(bufA, 128, col, quad, jt, pack_relu(acc[0], acc[1]), pack_relu(acc[2], acc[3]));
        }
        __syncthreads();
        short8 y2b[4];
#pragma unroll
        for (int kc = 0; kc < 4; ++kc) y2b[kc] = xread(bufA, 128, col, quad, kc);
        // T1 tiles jt = 3w..3w+2, K=128
#pragma unroll
        for (int ti = 0; ti < 3; ++ti) {
            int jt = 3 * w + ti;
            const u16* wr = w1m + (size_t)(jt * 16 + col) * 128 + quad * 8;
            f32x4 acc = bias4(b1m + jt * 16 + quad * 4);
#pragma unroll
            for (int kc = 0; kc < 4; ++kc)
                acc = MFMA16(*(const short8*)(wr + kc * 32), y2b[kc], acc, 0, 0, 0);
            xwrite(bufB, 192, col, quad, jt, pack_relu(acc[0], acc[1]), pack_relu(acc[2], acc[3]));
        }
        __syncthreads();
        short8 t1b[6];
#pragma unroll
        for (int kc = 0; kc < 6; ++kc) t1b[kc] = xread(bufB, 192, col, quad, kc);
        // T2 tile jt=w, K=192  (write to bufA @ stride 64 — Y2 reads all done)
        {
            const u16* wr = w2m + (size_t)(w * 16 + col) * 192 + quad * 8;
            f32x4 acc = bias4(b2m + w * 16 + quad * 4);
#pragma unroll
            for (int kc = 0; kc < 6; ++kc)
                acc = MFMA16(*(const short8*)(wr + kc * 32), t1b[kc], acc, 0, 0, 0);
            xwrite(bufA, 64, col, quad, w, pack_relu(acc[0], acc[1]), pack_relu(acc[2], acc[3]));
        }
        __syncthreads();
        short8 t2b0 = xread(bufA, 64, col, quad, 0);
        short8 t2b1 = xread(bufA, 64, col, quad, 1);
        // out tile jt=w, K=64, f32 store
        {
            const u16* wr = w3m + (size_t)(w * 16 + col) * 64 + quad * 8;
            f32x4 acc = bias4(b3m + w * 16 + quad * 4);
            acc = MFMA16(*(const short8*)(wr),      t2b0, acc, 0, 0, 0);
            acc = MFMA16(*(const short8*)(wr + 32), t2b1, acc, 0, 0, 0);
            float4 o;
            o.x = fmaxf(acc[0], 0.f); o.y = fmaxf(acc[1], 0.f);
            o.z = fmaxf(acc[2], 0.f); o.w = fmaxf(acc[3], 0.f);
            *(float4*)(outp + (size_t)(node0 + col) * 64 + w * 16 + quad * 4) = o;
        }
    }
}

// ---------------------------------------------------------------------------
extern "C" void kernel_launch(void* const* d_in, const int* in_sizes, int n_in,
                              void* d_out, int out_size, void* d_ws, size_t ws_size,
                              hipStream_t stream)
{
    const u16* x       = (const u16*)d_in[0];
    const int* edge    = (const int*)d_in[1];
    const u16* p1_pw   = (const u16*)d_in[3];
    const u16* p1_pb   = (const u16*)d_in[4];
    const u16* p1_wih  = (const u16*)d_in[5];
    const u16* p1_whh  = (const u16*)d_in[6];
    const u16* p1_bih  = (const u16*)d_in[7];
    const u16* p1_bhh  = (const u16*)d_in[8];
    const u16* p1_llw  = (const u16*)d_in[9];
    const u16* p1_llb  = (const u16*)d_in[10];
    const u16* p1_lrw  = (const u16*)d_in[11];
    const u16* p2_pw   = (const u16*)d_in[12];
    const u16* p2_pb   = (const u16*)d_in[13];
    const u16* p2_wih  = (const u16*)d_in[14];
    const u16* p2_whh  = (const u16*)d_in[15];
    const u16* p2_bih  = (const u16*)d_in[16];
    const u16* p2_bhh  = (const u16*)d_in[17];
    const u16* p2_llw  = (const u16*)d_in[18];
    const u16* p2_llb  = (const u16*)d_in[19];
    const u16* p2_lrw  = (const u16*)d_in[20];
    const u16* lin1w   = (const u16*)d_in[21];
    const u16* lin1b   = (const u16*)d_in[22];
    const u16* lin2w   = (const u16*)d_in[23];
    const u16* lin2b   = (const u16*)d_in[24];
    const u16* lin3w   = (const u16*)d_in[25];
    const u16* lin3b   = (const u16*)d_in[26];
    (void)n_in; (void)ws_size;

    const int N  = in_sizes[0] / 64;     // 50000
    const int E2 = in_sizes[1];          // 1600000
    const int* srcIdx = edge;

    // workspace: scaled weights 128KB @0; xp1 @1MB; xp2 @8MB; Y1 @15MB
    char* w = (char*)d_ws;
    u16* wss   = (u16*)(w);
    u16* xp1   = (u16*)(w + 1u  * 1024 * 1024);
    u16* xp2   = (u16*)(w + 8u  * 1024 * 1024);
    u16* bufY1 = (u16*)(w + 15u * 1024 * 1024);
    u16* wih1s = wss;
    u16* whh1s = wss + 16384;
    u16* wih2s = wss + 32768;
    u16* whh2s = wss + 49152;

    float* out_h    = (float*)d_out;
    float* out_edge = (float*)d_out + (size_t)N * 64;
    (void)out_size;

    const int gb  = (N + 63) / 64;       // 782 (xp1 GEMM blocks)
    const int gbl = (N + 15) / 16;       // 3125 (lstm blocks)
    const int n4 = E2 / 4;
    const int eb = (n4 + 255) / 256;     // 1563

    dim3 block(256);

    hipLaunchKernelGGL(k_pre, dim3(gb + eb + 4), block, 0, stream,
                       x, p1_pw, p1_pb, xp1, N, gb,
                       edge, out_edge, n4, eb,
                       p1_wih, p1_whh, p2_wih, p2_whh, wss);
    hipLaunchKernelGGL(lstm_mid, dim3(gbl), block, 0, stream,
                       xp1, srcIdx, wih1s, whh1s, p1_bih, p1_bhh,
                       x, p1_llw, p1_llb, p1_lrw, p2_pw, p2_pb, bufY1, xp2, N);
    hipLaunchKernelGGL(lstm_post, dim3(gbl), block, 0, stream,
                       xp2, srcIdx, wih2s, whh2s, p2_bih, p2_bhh,
                       bufY1, p2_llw, p2_llb, p2_lrw,
                       lin1w, lin1b, lin2w, lin2b, lin3w, lin3b, out_h, N);
}

// Round 10
// 356.316 us; speedup vs baseline: 1.6912x; 1.0307x over previous
//
#include <hip/hip_runtime.h>
#include <hip/hip_bf16.h>

typedef unsigned short u16;
typedef unsigned int u32;
typedef __attribute__((ext_vector_type(8))) short short8;    // 8 bf16 MFMA A/B frag
typedef __attribute__((ext_vector_type(4))) float f32x4;

#define KS1 1.44269504f   // log2(e)
#define KS2 2.88539008f   // 2*log2(e)

__device__ __forceinline__ float bf2f(u16 u) {
    union { u32 i; float f; } v; v.i = ((u32)u) << 16; return v.f;
}
__device__ __forceinline__ u16 f2bf(float f) {            // RNE
    union { float f; u32 i; } v; v.f = f;
    u32 r = v.i + 0x7fffu + ((v.i >> 16) & 1u);
    return (u16)(r >> 16);
}
// pack two f32 -> two bf16 (truncation) in ONE v_perm (h state only)
__device__ __forceinline__ u32 pack_bf2(float lo, float hi) {
    return __builtin_amdgcn_perm(__float_as_uint(hi), __float_as_uint(lo), 0x07060302u);
}
// relu + RNE pack (epilogue intermediates)
__device__ __forceinline__ u32 pack_relu(float a, float b) {
    return (u32)f2bf(fmaxf(a, 0.f)) | ((u32)f2bf(fmaxf(b, 0.f)) << 16);
}
__device__ __forceinline__ f32x4 bias4(const u16* b) {
    uint2 u = *(const uint2*)b;
    f32x4 r;
    r[0] = bf2f((u16)(u.x & 0xffffu)); r[1] = bf2f((u16)(u.x >> 16));
    r[2] = bf2f((u16)(u.y & 0xffffu)); r[3] = bf2f((u16)(u.y >> 16));
    return r;
}
// XOR-swizzled exchange buffer (proven bank-free: <=2-way).
// row = node row index (key (row&7) consistent for row and row+16)
__device__ __forceinline__ void xwrite(u16* buf, int D2, int row, int quad, int jt, u32 w0, u32 w1) {
    int ch = jt * 2 + (quad >> 1);
    *(uint2*)(buf + row * D2 + ((ch ^ (row & 7)) << 3) + ((quad & 1) << 2)) = (uint2){w0, w1};
}
__device__ __forceinline__ short8 xread(const u16* buf, int D2, int row, int quad, int kc) {
    return *(const short8*)(buf + row * D2 + (((kc * 4 + quad) ^ (row & 7)) << 3));
}
#define MFMA16 __builtin_amdgcn_mfma_f32_16x16x32_bf16

// ---------------------------------------------------------------------------
// k_pre: [0,gb) xp1 GEMM; [gb,gb+eb) edge cast; [gb+eb,+4) scaled weight copies
// ---------------------------------------------------------------------------
__global__ __launch_bounds__(256) void k_pre(
    const u16* __restrict__ X, const u16* __restrict__ pw, const u16* __restrict__ pb,
    u16* __restrict__ XP, int M, int gb,
    const int* __restrict__ e, float* __restrict__ eout, int n4, int eb,
    const u16* __restrict__ w1i, const u16* __restrict__ w1h,
    const u16* __restrict__ w2i, const u16* __restrict__ w2h,
    u16* __restrict__ wss)
{
    const int bid = blockIdx.x;
    const int tid = threadIdx.x;
    if (bid >= gb + eb) {
        int mi = bid - gb - eb;
        const u16* Wsrc = (mi == 0) ? w1i : (mi == 1) ? w1h : (mi == 2) ? w2i : w2h;
        u16* Wdst = wss + (size_t)mi * 16384;
        for (int idx = tid; idx < 16384; idx += 256) {
            int row = idx >> 6;
            float sc = (row >= 128 && row < 192) ? KS2 : KS1;
            Wdst[idx] = f2bf(bf2f(Wsrc[idx]) * sc);
        }
        return;
    }
    if (bid >= gb) {
        int i = (bid - gb) * 256 + tid;
        if (i < n4) {
            int4 v = *(const int4*)(e + (size_t)i * 4);
            float4 o;
            o.x = (float)v.x; o.y = (float)v.y; o.z = (float)v.z; o.w = (float)v.w;
            *(float4*)(eout + (size_t)i * 4) = o;
        }
        return;
    }
    const int lane = tid & 63;
    const int wave = tid >> 6;
    const int row0 = (bid * 4 + wave) * 16;
    if (row0 >= M) return;
    const int col  = lane & 15;
    const int quad = lane >> 4;

    f32x4 c1[4];
#pragma unroll
    for (int jt = 0; jt < 4; ++jt) c1[jt] = (f32x4){0.f, 0.f, 0.f, 0.f};
    {
        const u16* xrow = X  + (size_t)(row0 + col) * 64 + quad * 8;
        const u16* wrow = pw + (size_t)col * 64 + quad * 8;
#pragma unroll
        for (int kc = 0; kc < 64; kc += 32) {
            short8 a = *(const short8*)(xrow + kc);
#pragma unroll
            for (int jt = 0; jt < 4; ++jt) {
                short8 b = *(const short8*)(wrow + (size_t)jt * 16 * 64 + kc);
                c1[jt] = MFMA16(a, b, c1[jt], 0, 0, 0);
            }
        }
    }
#pragma unroll
    for (int jt = 0; jt < 4; ++jt) {
        float bias = bf2f(pb[jt * 16 + col]);
#pragma unroll
        for (int r = 0; r < 4; ++r) {
            float v = fmaxf(c1[jt][r] + bias, 0.f);
            XP[(size_t)(row0 + quad * 4 + r) * 64 + jt * 16 + col] = f2bf(v);
        }
    }
}

// ===========================================================================
// LSTM v5: 32 nodes / 4-wave block, 2 ILP streams (A,B) per wave.
// Wave w owns gate tiles {w,w+4,w+8,w+12}; ONE weight copy (64 VGPRs) feeds
// both streams. Stalls of one stream (exchange barrier, trans chain, gather)
// are filled by the other. One barrier per step, shared by both streams.
// ===========================================================================

#define NONLIN(ACC, CST, HW0, HW1)                                             \
    {                                                                          \
        float hv[4];                                                           \
        _Pragma("unroll") for (int r = 0; r < 4; ++r) {                        \
            float iv = ACC[0][r], fv = ACC[1][r], gv = ACC[2][r], ov = ACC[3][r]; \
            float e_i = __builtin_amdgcn_exp2f(-iv);                           \
            float e_f = __builtin_amdgcn_exp2f(-fv);                           \
            float e_g = __builtin_amdgcn_exp2f(gv);                            \
            float sf  = __builtin_amdgcn_rcpf(1.0f + e_f);                     \
            float rig = __builtin_amdgcn_rcpf((1.0f + e_i) * (1.0f + e_g));    \
            float tt  = __builtin_fmaf(e_g, KS2, -KS2);                        \
            float cn  = __builtin_fmaf(sf, CST[r], tt * rig);                  \
            CST[r] = cn;                                                       \
            float e_c = __builtin_amdgcn_exp2f(cn);                            \
            float e_o = __builtin_amdgcn_exp2f(-ov);                           \
            float roc = __builtin_amdgcn_rcpf((1.0f + e_o) * (1.0f + e_c));    \
            hv[r] = (e_c - 1.0f) * roc;                                        \
        }                                                                      \
        HW0 = pack_bf2(hv[0], hv[1]);                                          \
        HW1 = pack_bf2(hv[2], hv[3]);                                          \
    }

#define LSTM2_PROLOGUE                                                         \
    const int tid  = threadIdx.x;                                              \
    const int lane = tid & 63;                                                 \
    const int w    = tid >> 6;                                                 \
    const int col  = lane & 15;                                                \
    const int quad = lane >> 4;                                                \
    const int node0 = blockIdx.x * 32;                                         \
    if (node0 >= N) return;                                                    \
    const bool actB = (node0 + 32 <= N);                                       \
    const int nodeA = node0 + col;                                             \
    const int nodeB = actB ? (node0 + 16 + col) : nodeA;                       \
    {                                                                          \
        int j = tid;                                                           \
        float sc = (j >= 128 && j < 192) ? KS2 : KS1;                          \
        lds_b[j] = (bf2f(bih[j]) + bf2f(bhh[j])) * sc;                         \
    }                                                                          \
    short8 wf[8], hf[8];                                                       \
    _Pragma("unroll") for (int g = 0; g < 4; ++g) {                            \
        int jt = w + 4 * g;                                                    \
        const u16* wi = wihs + (size_t)(jt * 16 + col) * 64 + quad * 8;        \
        const u16* wh = whhs + (size_t)(jt * 16 + col) * 64 + quad * 8;        \
        wf[g * 2 + 0] = *(const short8*)(wi);                                  \
        wf[g * 2 + 1] = *(const short8*)(wi + 32);                             \
        hf[g * 2 + 0] = *(const short8*)(wh);                                  \
        hf[g * 2 + 1] = *(const short8*)(wh + 32);                             \
    }                                                                          \
    int4 sidxA = *(const int4*)(src + (size_t)nodeA * 16 + quad * 4);          \
    int4 sidxB = *(const int4*)(src + (size_t)nodeB * 16 + quad * 4);          \
    short8 xbA0, xbA1, xbB0, xbB1;                                             \
    {                                                                          \
        int sA = __shfl(sidxA.x, col, 64);                                     \
        const u16* pA = xp + (size_t)sA * 64 + quad * 8;                       \
        xbA0 = *(const short8*)pA; xbA1 = *(const short8*)(pA + 32);           \
        int sB = __shfl(sidxB.x, col, 64);                                     \
        const u16* pB = xp + (size_t)sB * 64 + quad * 8;                       \
        xbB0 = *(const short8*)pB; xbB1 = *(const short8*)(pB + 32);           \
    }

#define LSTM2_CORE_LOOP                                                        \
    short8 hbA0 = (short8){0,0,0,0,0,0,0,0};                                   \
    short8 hbA1 = hbA0, hbB0 = hbA0, hbB1 = hbA0;                              \
    float cA[4], cB[4];                                                        \
    _Pragma("unroll") for (int i = 0; i < 4; ++i) { cA[i] = 0.f; cB[i] = 0.f; }\
    __syncthreads();                                                           \
    _Pragma("unroll 1") for (int t = 0; t < 16; ++t) {                         \
        f32x4 accA[4], accB[4];                                                \
        _Pragma("unroll") for (int g = 0; g < 4; ++g) {                        \
            f32x4 bc = *(const f32x4*)(lds_b + (w + 4 * g) * 16 + quad * 4);   \
            accA[g] = MFMA16(wf[g * 2 + 0], xbA0, bc, 0, 0, 0);                \
            accB[g] = MFMA16(wf[g * 2 + 0], xbB0, bc, 0, 0, 0);                \
            accA[g] = MFMA16(wf[g * 2 + 1], xbA1, accA[g], 0, 0, 0);           \
            accB[g] = MFMA16(wf[g * 2 + 1], xbB1, accB[g], 0, 0, 0);           \
        }                                                                      \
        if (t < 15) {                                                          \
            int tn = t + 1;                                                    \
            int cvA = (tn & 2) ? ((tn & 1) ? sidxA.w : sidxA.z)                \
                               : ((tn & 1) ? sidxA.y : sidxA.x);               \
            int snA = __shfl(cvA, ((tn >> 2) << 4) + col, 64);                 \
            const u16* pA = xp + (size_t)snA * 64 + quad * 8;                  \
            xbA0 = *(const short8*)pA; xbA1 = *(const short8*)(pA + 32);       \
            int cvB = (tn & 2) ? ((tn & 1) ? sidxB.w : sidxB.z)                \
                               : ((tn & 1) ? sidxB.y : sidxB.x);               \
            int snB = __shfl(cvB, ((tn >> 2) << 4) + col, 64);                 \
            const u16* pB = xp + (size_t)snB * 64 + quad * 8;                  \
            xbB0 = *(const short8*)pB; xbB1 = *(const short8*)(pB + 32);       \
        }                                                                      \
        if (t > 0) {                                                           \
            _Pragma("unroll") for (int g = 0; g < 4; ++g) {                    \
                accA[g] = MFMA16(hf[g * 2 + 0], hbA0, accA[g], 0, 0, 0);       \
                accB[g] = MFMA16(hf[g * 2 + 0], hbB0, accB[g], 0, 0, 0);       \
                accA[g] = MFMA16(hf[g * 2 + 1], hbA1, accA[g], 0, 0, 0);       \
                accB[g] = MFMA16(hf[g * 2 + 1], hbB1, accB[g], 0, 0, 0);       \
            }                                                                  \
        }                                                                      \
        u32 hwA0, hwA1, hwB0, hwB1;                                            \
        NONLIN(accA, cA, hwA0, hwA1)                                           \
        NONLIN(accB, cB, hwB0, hwB1)                                           \
        u16* hbuf = lds_h[t & 1];                                              \
        xwrite(hbuf, 64, col,      quad, w, hwA0, hwA1);                       \
        xwrite(hbuf, 64, col + 16, quad, w, hwB0, hwB1);                       \
        __syncthreads();                                                       \
        hbA0 = xread(hbuf, 64, col,      quad, 0);                             \
        hbA1 = xread(hbuf, 64, col,      quad, 1);                             \
        hbB0 = xread(hbuf, 64, col + 16, quad, 0);                             \
        hbB1 = xread(hbuf, 64, col + 16, quad, 1);                             \
    }

// ---------------------------------------------------------------------------
// lstm_mid: layer-1 LSTM + fused Y1 + xp2
// ---------------------------------------------------------------------------
__global__ __launch_bounds__(256) void lstm_mid(
    const u16* __restrict__ xp, const int* __restrict__ src,
    const u16* __restrict__ wihs, const u16* __restrict__ whhs,
    const u16* __restrict__ bih, const u16* __restrict__ bhh,
    const u16* __restrict__ X,                                   // root x [N,64]
    const u16* __restrict__ llw, const u16* __restrict__ llb,
    const u16* __restrict__ lrw,
    const u16* __restrict__ pw, const u16* __restrict__ pb,
    u16* __restrict__ Y1, u16* __restrict__ XP2, int N)
{
    __shared__ float lds_b[256];        // 1KB scaled bias'
    __shared__ u16 lds_h[2][32 * 64];   // 8KB h double buffer
    __shared__ u16 bufY[32 * 64];       // 4KB Y1 exchange

    LSTM2_PROLOGUE
    LSTM2_CORE_LOOP

    // ---- epilogue: hb* = H B-frags for both groups ----
    {
        const u16* wr  = llw + (size_t)(w * 16 + col) * 64 + quad * 8;
        short8 ll0 = *(const short8*)wr, ll1 = *(const short8*)(wr + 32);
        const u16* wr2 = lrw + (size_t)(w * 16 + col) * 64 + quad * 8;
        short8 lr0 = *(const short8*)wr2, lr1 = *(const short8*)(wr2 + 32);
        f32x4 bY = bias4(llb + w * 16 + quad * 4);

        const u16* xrA = X + (size_t)nodeA * 64 + quad * 8;
        short8 rxA0 = *(const short8*)xrA, rxA1 = *(const short8*)(xrA + 32);
        const u16* xrB = X + (size_t)nodeB * 64 + quad * 8;
        short8 rxB0 = *(const short8*)xrB, rxB1 = *(const short8*)(xrB + 32);

        f32x4 aA = MFMA16(ll0, hbA0, bY, 0, 0, 0);
        aA = MFMA16(ll1, hbA1, aA, 0, 0, 0);
        aA = MFMA16(lr0, rxA0, aA, 0, 0, 0);
        aA = MFMA16(lr1, rxA1, aA, 0, 0, 0);
        f32x4 aB = MFMA16(ll0, hbB0, bY, 0, 0, 0);
        aB = MFMA16(ll1, hbB1, aB, 0, 0, 0);
        aB = MFMA16(lr0, rxB0, aB, 0, 0, 0);
        aB = MFMA16(lr1, rxB1, aB, 0, 0, 0);

        u32 yA0 = pack_relu(aA[0], aA[1]), yA1 = pack_relu(aA[2], aA[3]);
        u32 yB0 = pack_relu(aB[0], aB[1]), yB1 = pack_relu(aB[2], aB[3]);
        *(uint2*)(Y1 + (size_t)nodeA * 64 + w * 16 + quad * 4) = (uint2){yA0, yA1};
        if (actB) *(uint2*)(Y1 + (size_t)nodeB * 64 + w * 16 + quad * 4) = (uint2){yB0, yB1};
        xwrite(bufY, 64, col,      quad, w, yA0, yA1);
        xwrite(bufY, 64, col + 16, quad, w, yB0, yB1);
        __syncthreads();

        const u16* wp = pw + (size_t)(w * 16 + col) * 64 + quad * 8;
        short8 p0 = *(const short8*)wp, p1 = *(const short8*)(wp + 32);
        f32x4 bp = bias4(pb + w * 16 + quad * 4);

        short8 ybA0 = xread(bufY, 64, col,      quad, 0);
        short8 ybA1 = xread(bufY, 64, col,      quad, 1);
        short8 ybB0 = xread(bufY, 64, col + 16, quad, 0);
        short8 ybB1 = xread(bufY, 64, col + 16, quad, 1);

        f32x4 a2A = MFMA16(p0, ybA0, bp, 0, 0, 0);
        a2A = MFMA16(p1, ybA1, a2A, 0, 0, 0);
        f32x4 a2B = MFMA16(p0, ybB0, bp, 0, 0, 0);
        a2B = MFMA16(p1, ybB1, a2B, 0, 0, 0);

        *(uint2*)(XP2 + (size_t)nodeA * 64 + w * 16 + quad * 4) =
            (uint2){pack_relu(a2A[0], a2A[1]), pack_relu(a2A[2], a2A[3])};
        if (actB) *(uint2*)(XP2 + (size_t)nodeB * 64 + w * 16 + quad * 4) =
            (uint2){pack_relu(a2B[0], a2B[1]), pack_relu(a2B[2], a2B[3])};
    }
}

// ---------------------------------------------------------------------------
// lstm_post: layer-2 LSTM + fused Y2[128] -> T1[192] -> T2[64] -> out[64] f32
// ---------------------------------------------------------------------------
__global__ __launch_bounds__(256) void lstm_post(
    const u16* __restrict__ xp, const int* __restrict__ src,
    const u16* __restrict__ wihs, const u16* __restrict__ whhs,
    const u16* __restrict__ bih, const u16* __restrict__ bhh,
    const u16* __restrict__ Y1,                                  // [N,64]
    const u16* __restrict__ llw2, const u16* __restrict__ llb2,
    const u16* __restrict__ lrw2,                                // [128,64],[128],[128,64]
    const u16* __restrict__ w1m, const u16* __restrict__ b1m,    // [192,128],[192]
    const u16* __restrict__ w2m, const u16* __restrict__ b2m,    // [64,192],[64]
    const u16* __restrict__ w3m, const u16* __restrict__ b3m,    // [64,64],[64]
    float* __restrict__ outp, int N)
{
    __shared__ float lds_b[256];        // 1KB
    __shared__ u16 lds_h[2][32 * 64];   // 8KB
    __shared__ u16 bufA[32 * 128];      // 8KB Y2 exchange (reused for T2 @ stride 64)
    __shared__ u16 bufB[32 * 192];      // 12KB T1 exchange

    LSTM2_PROLOGUE
    LSTM2_CORE_LOOP

    // ---- epilogue ----
    {
        const u16* yrA = Y1 + (size_t)nodeA * 64 + quad * 8;
        short8 ryA0 = *(const short8*)yrA, ryA1 = *(const short8*)(yrA + 32);
        const u16* yrB = Y1 + (size_t)nodeB * 64 + quad * 8;
        short8 ryB0 = *(const short8*)yrB, ryB1 = *(const short8*)(yrB + 32);

        // Y2 tiles jt = 2w, 2w+1
#pragma unroll
        for (int ti = 0; ti < 2; ++ti) {
            int jt = 2 * w + ti;
            const u16* wr = llw2 + (size_t)(jt * 16 + col) * 64 + quad * 8;
            short8 l0 = *(const short8*)wr, l1 = *(const short8*)(wr + 32);
            const u16* wr2 = lrw2 + (size_t)(jt * 16 + col) * 64 + quad * 8;
            short8 r0 = *(const short8*)wr2, r1 = *(const short8*)(wr2 + 32);
            f32x4 b0 = bias4(llb2 + jt * 16 + quad * 4);
            f32x4 aA = MFMA16(l0, hbA0, b0, 0, 0, 0);
            aA = MFMA16(l1, hbA1, aA, 0, 0, 0);
            aA = MFMA16(r0, ryA0, aA, 0, 0, 0);
            aA = MFMA16(r1, ryA1, aA, 0, 0, 0);
            xwrite(bufA, 128, col, quad, jt, pack_relu(aA[0], aA[1]), pack_relu(aA[2], aA[3]));
            f32x4 aB = MFMA16(l0, hbB0, b0, 0, 0, 0);
            aB = MFMA16(l1, hbB1, aB, 0, 0, 0);
            aB = MFMA16(r0, ryB0, aB, 0, 0, 0);
            aB = MFMA16(r1, ryB1, aB, 0, 0, 0);
            xwrite(bufA, 128, col + 16, quad, jt, pack_relu(aB[0], aB[1]), pack_relu(aB[2], aB[3]));
        }
        __syncthreads();

        short8 y2A[4], y2B[4];
#pragma unroll
        for (int kc = 0; kc < 4; ++kc) {
            y2A[kc] = xread(bufA, 128, col,      quad, kc);
            y2B[kc] = xread(bufA, 128, col + 16, quad, kc);
        }
        // T1 tiles jt = 3w..3w+2, K=128
#pragma unroll
        for (int ti = 0; ti < 3; ++ti) {
            int jt = 3 * w + ti;
            const u16* wr = w1m + (size_t)(jt * 16 + col) * 128 + quad * 8;
            short8 wk[4];
#pragma unroll
            for (int kc = 0; kc < 4; ++kc) wk[kc] = *(const short8*)(wr + kc * 32);
            f32x4 b1v = bias4(b1m + jt * 16 + quad * 4);
            f32x4 aA = b1v, aB = b1v;
#pragma unroll
            for (int kc = 0; kc < 4; ++kc) {
                aA = MFMA16(wk[kc], y2A[kc], aA, 0, 0, 0);
                aB = MFMA16(wk[kc], y2B[kc], aB, 0, 0, 0);
            }
            xwrite(bufB, 192, col,      quad, jt, pack_relu(aA[0], aA[1]), pack_relu(aA[2], aA[3]));
            xwrite(bufB, 192, col + 16, quad, jt, pack_relu(aB[0], aB[1]), pack_relu(aB[2], aB[3]));
        }
        __syncthreads();

        short8 t1A[6], t1B[6];
#pragma unroll
        for (int kc = 0; kc < 6; ++kc) {
            t1A[kc] = xread(bufB, 192, col,      quad, kc);
            t1B[kc] = xread(bufB, 192, col + 16, quad, kc);
        }
        // T2 tile jt=w, K=192 (bufA reuse @ stride 64 — Y2 reads completed pre-barrier)
        {
            const u16* wr = w2m + (size_t)(w * 16 + col) * 192 + quad * 8;
            f32x4 b2v = bias4(b2m + w * 16 + quad * 4);
            f32x4 aA = b2v, aB = b2v;
#pragma unroll
            for (int kc = 0; kc < 6; ++kc) {
                short8 wk = *(const short8*)(wr + kc * 32);
                aA = MFMA16(wk, t1A[kc], aA, 0, 0, 0);
                aB = MFMA16(wk, t1B[kc], aB, 0, 0, 0);
            }
            xwrite(bufA, 64, col,      quad, w, pack_relu(aA[0], aA[1]), pack_relu(aA[2], aA[3]));
            xwrite(bufA, 64, col + 16, quad, w, pack_relu(aB[0], aB[1]), pack_relu(aB[2], aB[3]));
        }
        __syncthreads();

        short8 t2A0 = xread(bufA, 64, col,      quad, 0);
        short8 t2A1 = xread(bufA, 64, col,      quad, 1);
        short8 t2B0 = xread(bufA, 64, col + 16, quad, 0);
        short8 t2B1 = xread(bufA, 64, col + 16, quad, 1);
        // out tile jt=w, K=64, f32 store
        {
            const u16* wr = w3m + (size_t)(w * 16 + col) * 64 + quad * 8;
            short8 l0 = *(const short8*)wr, l1 = *(const short8*)(wr + 32);
            f32x4 b3v = bias4(b3m + w * 16 + quad * 4);
            f32x4 aA = MFMA16(l0, t2A0, b3v, 0, 0, 0);
            aA = MFMA16(l1, t2A1, aA, 0, 0, 0);
            f32x4 aB = MFMA16(l0, t2B0, b3v, 0, 0, 0);
            aB = MFMA16(l1, t2B1, aB, 0, 0, 0);
            float4 oA;
            oA.x = fmaxf(aA[0], 0.f); oA.y = fmaxf(aA[1], 0.f);
            oA.z = fmaxf(aA[2], 0.f); oA.w = fmaxf(aA[3], 0.f);
            *(float4*)(outp + (size_t)nodeA * 64 + w * 16 + quad * 4) = oA;
            if (actB) {
                float4 oB;
                oB.x = fmaxf(aB[0], 0.f); oB.y = fmaxf(aB[1], 0.f);
                oB.z = fmaxf(aB[2], 0.f); oB.w = fmaxf(aB[3], 0.f);
                *(float4*)(outp + (size_t)nodeB * 64 + w * 16 + quad * 4) = oB;
            }
        }
    }
}

// ---------------------------------------------------------------------------
extern "C" void kernel_launch(void* const* d_in, const int* in_sizes, int n_in,
                              void* d_out, int out_size, void* d_ws, size_t ws_size,
                              hipStream_t stream)
{
    const u16* x       = (const u16*)d_in[0];
    const int* edge    = (const int*)d_in[1];
    const u16* p1_pw   = (const u16*)d_in[3];
    const u16* p1_pb   = (const u16*)d_in[4];
    const u16* p1_wih  = (const u16*)d_in[5];
    const u16* p1_whh  = (const u16*)d_in[6];
    const u16* p1_bih  = (const u16*)d_in[7];
    const u16* p1_bhh  = (const u16*)d_in[8];
    const u16* p1_llw  = (const u16*)d_in[9];
    const u16* p1_llb  = (const u16*)d_in[10];
    const u16* p1_lrw  = (const u16*)d_in[11];
    const u16* p2_pw   = (const u16*)d_in[12];
    const u16* p2_pb   = (const u16*)d_in[13];
    const u16* p2_wih  = (const u16*)d_in[14];
    const u16* p2_whh  = (const u16*)d_in[15];
    const u16* p2_bih  = (const u16*)d_in[16];
    const u16* p2_bhh  = (const u16*)d_in[17];
    const u16* p2_llw  = (const u16*)d_in[18];
    const u16* p2_llb  = (const u16*)d_in[19];
    const u16* p2_lrw  = (const u16*)d_in[20];
    const u16* lin1w   = (const u16*)d_in[21];
    const u16* lin1b   = (const u16*)d_in[22];
    const u16* lin2w   = (const u16*)d_in[23];
    const u16* lin2b   = (const u16*)d_in[24];
    const u16* lin3w   = (const u16*)d_in[25];
    const u16* lin3b   = (const u16*)d_in[26];
    (void)n_in; (void)ws_size;

    const int N  = in_sizes[0] / 64;     // 50000
    const int E2 = in_sizes[1];          // 1600000
    const int* srcIdx = edge;

    // workspace: scaled weights 128KB @0; xp1 @1MB; xp2 @8MB; Y1 @15MB
    char* w = (char*)d_ws;
    u16* wss   = (u16*)(w);
    u16* xp1   = (u16*)(w + 1u  * 1024 * 1024);
    u16* xp2   = (u16*)(w + 8u  * 1024 * 1024);
    u16* bufY1 = (u16*)(w + 15u * 1024 * 1024);
    u16* wih1s = wss;
    u16* whh1s = wss + 16384;
    u16* wih2s = wss + 32768;
    u16* whh2s = wss + 49152;

    float* out_h    = (float*)d_out;
    float* out_edge = (float*)d_out + (size_t)N * 64;
    (void)out_size;

    const int gb  = (N + 63) / 64;       // 782 (xp1 GEMM blocks)
    const int gbl = (N + 31) / 32;       // 1563 (lstm blocks, 32 nodes each)
    const int n4 = E2 / 4;
    const int eb = (n4 + 255) / 256;     // 1563

    dim3 block(256);

    hipLaunchKernelGGL(k_pre, dim3(gb + eb + 4), block, 0, stream,
                       x, p1_pw, p1_pb, xp1, N, gb,
                       edge, out_edge, n4, eb,
                       p1_wih, p1_whh, p2_wih, p2_whh, wss);
    hipLaunchKernelGGL(lstm_mid, dim3(gbl), block, 0, stream,
                       xp1, srcIdx, wih1s, whh1s, p1_bih, p1_bhh,
                       x, p1_llw, p1_llb, p1_lrw, p2_pw, p2_pb, bufY1, xp2, N);
    hipLaunchKernelGGL(lstm_post, dim3(gbl), block, 0, stream,
                       xp2, srcIdx, wih2s, whh2s, p2_bih, p2_bhh,
                       bufY1, p2_llw, p2_llb, p2_lrw,
                       lin1w, lin1b, lin2w, lin2b, lin3w, lin3b, out_h, N);
}